// Round 7
// baseline (954.856 us; speedup 1.0000x reference)
//
#include <hip/hip_runtime.h>
#include <hip/hip_bf16.h>

typedef __bf16 bf16x8_t __attribute__((ext_vector_type(8)));
typedef float  f32x4_t  __attribute__((ext_vector_type(4)));

__device__ inline bf16x8_t ld_bf16x8(const __hip_bfloat16* p) {
    return *reinterpret_cast<const bf16x8_t*>(p);
}
__device__ inline bf16x8_t zero_bf16x8() {
    bf16x8_t z;
#pragma unroll
    for (int i = 0; i < 8; ++i) z[i] = (__bf16)0.0f;
    return z;
}

// Exact 3-way bf16 split: v == h + m + l exactly (truncation-based).
__device__ inline void split3f(float v, __bf16& h, __bf16& m, __bf16& l) {
    unsigned u;  __builtin_memcpy(&u, &v, 4);
    unsigned uh = u & 0xffff0000u;
    float fh;    __builtin_memcpy(&fh, &uh, 4);
    float r = v - fh;
    unsigned ur; __builtin_memcpy(&ur, &r, 4);
    unsigned um = ur & 0xffff0000u;
    float fm;    __builtin_memcpy(&fm, &um, 4);
    float r2 = r - fm;
    unsigned ul; __builtin_memcpy(&ul, &r2, 4);
    unsigned short hs = (unsigned short)(uh >> 16);
    unsigned short ms = (unsigned short)(um >> 16);
    unsigned short ls = (unsigned short)(ul >> 16);
    __builtin_memcpy(&h, &hs, 2);
    __builtin_memcpy(&m, &ms, 2);
    __builtin_memcpy(&l, &ls, 2);
}

// ---------------------------------------------------------------------------
// enc1: conv 4x4 s2 pad1, CIN=3, COUT=32, exact fp32 (validated round 3).
// ---------------------------------------------------------------------------
__global__ __launch_bounds__(256) void enc1_kernel(
    const float* __restrict__ x, const float* __restrict__ w,
    const float* __restrict__ bias, float* __restrict__ y)
{
    __shared__ float xs[34*66*3];
    __shared__ float wsm[1536];

    const int n  = blockIdx.x >> 3;
    const int th = (blockIdx.x >> 1) & 3;
    const int tw = blockIdx.x & 1;
    const int HO0 = th*16, WO0 = tw*32;
    const int HI0 = 2*HO0 - 1, WI0 = 2*WO0 - 1;
    const int t = threadIdx.x;

    for (int i = t; i < 1536; i += 256) wsm[i] = w[i];
    for (int i = t; i < 34*66*3; i += 256) {
        int row = i / 198; int j = i - row*198;
        int wi_l = j / 3;  int c = j - wi_l*3;
        int hi = HI0 + row, wi = WI0 + wi_l;
        float v = 0.0f;
        if (hi >= 0 && hi < 128 && wi >= 0 && wi < 128)
            v = x[((n*128 + hi)*128 + wi)*3 + c];
        xs[i] = v;
    }
    __syncthreads();

    const int wl = t & 15, hl = t >> 4;
    float acc0[32], acc1[32];
#pragma unroll
    for (int f4 = 0; f4 < 8; ++f4) {
        float4 bv = *(const float4*)(bias + 4*f4);
        acc0[4*f4+0]=bv.x; acc0[4*f4+1]=bv.y; acc0[4*f4+2]=bv.z; acc0[4*f4+3]=bv.w;
        acc1[4*f4+0]=bv.x; acc1[4*f4+1]=bv.y; acc1[4*f4+2]=bv.z; acc1[4*f4+3]=bv.w;
    }
    for (int r = 0; r < 4; ++r) {
#pragma unroll
        for (int s = 0; s < 4; ++s) {
#pragma unroll
            for (int c = 0; c < 3; ++c) {
                float xv0 = xs[(2*hl + r)*198 + (2*wl + s)*3 + c];
                float xv1 = xs[(2*hl + r)*198 + (2*(wl+16) + s)*3 + c];
                const float* wp = wsm + ((r*4 + s)*3 + c)*32;
#pragma unroll
                for (int f4 = 0; f4 < 8; ++f4) {
                    float4 wv = *(const float4*)(wp + 4*f4);
                    acc0[4*f4+0] = fmaf(xv0, wv.x, acc0[4*f4+0]);
                    acc0[4*f4+1] = fmaf(xv0, wv.y, acc0[4*f4+1]);
                    acc0[4*f4+2] = fmaf(xv0, wv.z, acc0[4*f4+2]);
                    acc0[4*f4+3] = fmaf(xv0, wv.w, acc0[4*f4+3]);
                    acc1[4*f4+0] = fmaf(xv1, wv.x, acc1[4*f4+0]);
                    acc1[4*f4+1] = fmaf(xv1, wv.y, acc1[4*f4+1]);
                    acc1[4*f4+2] = fmaf(xv1, wv.z, acc1[4*f4+2]);
                    acc1[4*f4+3] = fmaf(xv1, wv.w, acc1[4*f4+3]);
                }
            }
        }
    }
    float* y0 = y + ((size_t)((n*64 + HO0 + hl)*64) + WO0 + wl)*32;
#pragma unroll
    for (int f4 = 0; f4 < 8; ++f4) {
        float4 o0 = make_float4(fmaxf(acc0[4*f4+0],0.f), fmaxf(acc0[4*f4+1],0.f),
                                fmaxf(acc0[4*f4+2],0.f), fmaxf(acc0[4*f4+3],0.f));
        *(float4*)(y0 + 4*f4) = o0;
    }
    float* y1 = y0 + 16*32;
#pragma unroll
    for (int f4 = 0; f4 < 8; ++f4) {
        float4 o1 = make_float4(fmaxf(acc1[4*f4+0],0.f), fmaxf(acc1[4*f4+1],0.f),
                                fmaxf(acc1[4*f4+2],0.f), fmaxf(acc1[4*f4+3],0.f));
        *(float4*)(y1 + 4*f4) = o1;
    }
}

// ---------------------------------------------------------------------------
// Weight prep.
// ---------------------------------------------------------------------------
__global__ void prep_wt(const float* __restrict__ w, __hip_bfloat16* __restrict__ wt,
                        int TAPS, int CIN, int COUT)
{
    int i = blockIdx.x*256 + threadIdx.x;
    if (i >= TAPS*CIN*COUT) return;
    int c = i % CIN; int rem = i / CIN;
    int f = rem % COUT; int tap = rem / COUT;
    wt[i] = __float2bfloat16(w[(tap*CIN + c)*COUT + f]);
}

__global__ void prep_wt3(const float* __restrict__ w,
                         __hip_bfloat16* __restrict__ wh, __hip_bfloat16* __restrict__ wm,
                         __hip_bfloat16* __restrict__ wl,
                         int TAPS, int CIN, int COUT)
{
    int i = blockIdx.x*256 + threadIdx.x;
    if (i >= TAPS*CIN*COUT) return;
    int c = i % CIN; int rem = i / CIN;
    int f = rem % COUT; int tap = rem / COUT;
    float v = w[(tap*CIN + c)*COUT + f];
    __bf16 h, m, l;
    split3f(v, h, m, l);
    ((__bf16*)wh)[i] = h; ((__bf16*)wm)[i] = m; ((__bf16*)wl)[i] = l;
}

// ---------------------------------------------------------------------------
// bf16x3 MFMA encoder conv. NSPLIT: COUT tiles divided across blockIdx.y
// (raises occupancy for small grids; numerics per output element unchanged).
// ---------------------------------------------------------------------------
template<int R,int S,int CIN,int COUT,int IWL,int OWL,int STR,int PAD,int ACT,int INF32,int OUTF32,int NSPLIT>
__global__ __launch_bounds__(256) void mfma_enc3(
    const float* __restrict__ xf32,
    const __hip_bfloat16* __restrict__ xh, const __hip_bfloat16* __restrict__ xm,
    const __hip_bfloat16* __restrict__ xl,
    const __hip_bfloat16* __restrict__ wh, const __hip_bfloat16* __restrict__ wm,
    const __hip_bfloat16* __restrict__ wl,
    const float* __restrict__ bias,
    __hip_bfloat16* __restrict__ yh, __hip_bfloat16* __restrict__ ym,
    __hip_bfloat16* __restrict__ yl2,
    float* __restrict__ yf)
{
    constexpr int IW = 1 << IWL, OW = 1 << OWL;
    constexpr int NF = COUT / 16 / NSPLIT, KC = CIN / 32;
    const int nf0 = blockIdx.y * NF;          // COUT-tile offset
    const int t = threadIdx.x;
    const int wave = t >> 6, lane = t & 63;
    const int l15 = lane & 15, quad = lane >> 4;

    const int m  = blockIdx.x*64 + wave*16 + l15;
    const int wp_ = m & (OW-1);
    const int hp_ = (m >> OWL) & (OW-1);
    const int np_ = m >> (2*OWL);

    f32x4_t acc[NF];
#pragma unroll
    for (int nf = 0; nf < NF; ++nf) {
        float bv = bias[(nf0 + nf)*16 + l15];
        acc[nf][0] = bv; acc[nf][1] = bv; acc[nf][2] = bv; acc[nf][3] = bv;
    }
    const bf16x8_t zv = zero_bf16x8();

#pragma unroll
    for (int r = 0; r < R; ++r) {
#pragma unroll
        for (int s = 0; s < S; ++s) {
            const int hi = hp_*STR - PAD + r;
            const int wi = wp_*STR - PAD + s;
            const bool v = (hi >= 0) && (hi < IW) && (wi >= 0) && (wi < IW);
            const int hic = v ? hi : 0, wic = v ? wi : 0;
            const size_t abase = ((size_t)(np_*IW + hic)*IW + wic)*CIN + quad*8;
            const size_t bbase = (size_t)(r*S + s)*COUT*CIN + l15*CIN + quad*8;
#pragma unroll
            for (int kc = 0; kc < KC; ++kc) {
                bf16x8_t ah, am_, al_;
                if (INF32) {
                    float xv[8];
                    if (v) {
                        *(float4*)(xv+0) = *(const float4*)(xf32 + abase + kc*32);
                        *(float4*)(xv+4) = *(const float4*)(xf32 + abase + kc*32 + 4);
                    } else {
#pragma unroll
                        for (int j = 0; j < 8; ++j) xv[j] = 0.0f;
                    }
#pragma unroll
                    for (int j = 0; j < 8; ++j) {
                        __bf16 th, tm, tl;
                        split3f(xv[j], th, tm, tl);
                        ah[j] = th; am_[j] = tm; al_[j] = tl;
                    }
                } else {
                    ah  = v ? ld_bf16x8(xh + abase + kc*32) : zv;
                    am_ = v ? ld_bf16x8(xm + abase + kc*32) : zv;
                    al_ = v ? ld_bf16x8(xl + abase + kc*32) : zv;
                }
#pragma unroll
                for (int nf = 0; nf < NF; ++nf) {
                    const size_t bo = bbase + (size_t)(nf0 + nf)*16*CIN + kc*32;
                    bf16x8_t bh = ld_bf16x8(wh + bo);
                    bf16x8_t bm = ld_bf16x8(wm + bo);
                    bf16x8_t bl = ld_bf16x8(wl + bo);
                    // small terms first
                    acc[nf] = __builtin_amdgcn_mfma_f32_16x16x32_bf16(al_, bh, acc[nf], 0, 0, 0);
                    acc[nf] = __builtin_amdgcn_mfma_f32_16x16x32_bf16(ah,  bl, acc[nf], 0, 0, 0);
                    acc[nf] = __builtin_amdgcn_mfma_f32_16x16x32_bf16(am_, bm, acc[nf], 0, 0, 0);
                    acc[nf] = __builtin_amdgcn_mfma_f32_16x16x32_bf16(am_, bh, acc[nf], 0, 0, 0);
                    acc[nf] = __builtin_amdgcn_mfma_f32_16x16x32_bf16(ah,  bm, acc[nf], 0, 0, 0);
                    acc[nf] = __builtin_amdgcn_mfma_f32_16x16x32_bf16(ah,  bh, acc[nf], 0, 0, 0);
                }
            }
        }
    }

#pragma unroll
    for (int nf = 0; nf < NF; ++nf) {
#pragma unroll
        for (int i = 0; i < 4; ++i) {
            int mo = blockIdx.x*64 + wave*16 + quad*4 + i;
            int wo = mo & (OW-1), ho = (mo >> OWL) & (OW-1), no = mo >> (2*OWL);
            size_t oidx = ((size_t)(no*OW + ho)*OW + wo)*COUT + (nf0 + nf)*16 + l15;
            float vv = acc[nf][i];
            if (ACT) vv = fmaxf(vv, 0.0f);
            if (OUTF32) {
                yf[oidx] = vv;
            } else {
                __bf16 h, mm2, l;
                split3f(vv, h, mm2, l);
                ((__bf16*)yh)[oidx]  = h;
                ((__bf16*)ym)[oidx]  = mm2;
                ((__bf16*)yl2)[oidx] = l;
            }
        }
    }
}

// ---------------------------------------------------------------------------
// MFMA decoder layer: plain bf16. NSPLIT over blockIdx.z (CONVT) / .y (conv).
// ---------------------------------------------------------------------------
template<int CIN,int COUT,int SWL,int CONVT,int NSPLIT>
__global__ __launch_bounds__(256) void mfma_dec(
    const __hip_bfloat16* __restrict__ xin,
    const __hip_bfloat16* __restrict__ wt,
    const float* __restrict__ bias,
    __hip_bfloat16* __restrict__ yout)
{
    constexpr int SW = 1 << SWL;
    constexpr int NF = COUT / 16 / NSPLIT;
    const int ph = CONVT ? (int)(blockIdx.y >> 1) : 0;
    const int pw = CONVT ? (int)(blockIdx.y & 1) : 0;
    const int nf0 = (CONVT ? (int)blockIdx.z : (int)blockIdx.y) * NF;
    const int t = threadIdx.x;
    const int wave = t >> 6, lane = t & 63;
    const int l15 = lane & 15, quad = lane >> 4;

    const int m  = blockIdx.x*64 + wave*16 + l15;
    const int wp_ = m & (SW-1);
    const int hp_ = (m >> SWL) & (SW-1);
    const int np_ = m >> (2*SWL);

    f32x4_t acc[NF];
#pragma unroll
    for (int nf = 0; nf < NF; ++nf) {
        float bv = bias[(nf0 + nf)*16 + l15];
        acc[nf][0] = bv; acc[nf][1] = bv; acc[nf][2] = bv; acc[nf][3] = bv;
    }
    const bf16x8_t zv = zero_bf16x8();

#pragma unroll
    for (int rr = 0; rr < 2; ++rr) {
#pragma unroll
        for (int ss = 0; ss < 2; ++ss) {
            const int hi = hp_ + ph - 1 + rr;
            const int wi = wp_ + pw - 1 + ss;
            const bool v = (hi >= 0) && (hi < SW) && (wi >= 0) && (wi < SW);
            const int hic = v ? hi : 0, wic = v ? wi : 0;
            const int widx = CONVT ? ((ph + 2*rr)*4 + (pw + 2*ss)) : (rr*2 + ss);
            const __hip_bfloat16* ap = xin + (size_t)((np_*SW + hic)*SW + wic)*CIN + quad*8;
            const __hip_bfloat16* bp = wt + (size_t)(widx*COUT)*CIN + l15*CIN + quad*8;
#pragma unroll
            for (int k0 = 0; k0 < CIN; k0 += 32) {
                bf16x8_t a = v ? ld_bf16x8(ap + k0) : zv;
#pragma unroll
                for (int nf = 0; nf < NF; ++nf) {
                    bf16x8_t b = ld_bf16x8(bp + (size_t)(nf0 + nf)*16*CIN + k0);
                    acc[nf] = __builtin_amdgcn_mfma_f32_16x16x32_bf16(a, b, acc[nf], 0, 0, 0);
                }
            }
        }
    }

    constexpr int HOUT = CONVT ? 2*SW : SW;
#pragma unroll
    for (int nf = 0; nf < NF; ++nf) {
#pragma unroll
        for (int i = 0; i < 4; ++i) {
            int mo = blockIdx.x*64 + wave*16 + quad*4 + i;
            int wo = mo & (SW-1), ho = (mo >> SWL) & (SW-1), no = mo >> (2*SWL);
            int hoo = CONVT ? 2*ho + ph : ho;
            int woo = CONVT ? 2*wo + pw : wo;
            float vv = fmaxf(acc[nf][i], 0.0f);
            yout[((size_t)(no*HOUT + hoo)*HOUT + woo)*COUT + (nf0 + nf)*16 + l15] = __float2bfloat16(vv);
        }
    }
}

// ---------------------------------------------------------------------------
// dec4: convT 4x4 s2, CIN=32 (bf16 in), COUT=3, sigmoid, fp32 math.
// ---------------------------------------------------------------------------
__global__ __launch_bounds__(256) void dec4_kernel(
    const __hip_bfloat16* __restrict__ x, const float* __restrict__ w,
    const float* __restrict__ bias, float* __restrict__ y)
{
    __shared__ float xs[6*66*33];
    __shared__ float ws[4*32*3];

    const int ph = blockIdx.y >> 1, pw = blockIdx.y & 1;
    const int n  = blockIdx.x >> 4;
    const int R0 = (blockIdx.x & 15) * 4;
    const int t  = threadIdx.x;

    if (t < 384) {
        int tap = t / 96, rem = t - tap*96;
        int rr = tap >> 1, ss = tap & 1;
        int gtap = (ph + 2*rr)*4 + (pw + 2*ss);
        ws[t] = w[gtap*96 + rem];
    }
    for (int slot = t; slot < 6*66*4; slot += 256) {
        int row = slot / 264;
        int rem = slot - row*264;
        int yy = rem >> 2, c8 = rem & 3;
        int xi = R0 - 1 + row;
        float4 raw = make_float4(0.f,0.f,0.f,0.f);
        if (yy >= 1 && yy <= 64 && xi >= 0 && xi < 64)
            raw = *(const float4*)((const char*)x + (size_t)((((n*64 + xi)*64) + (yy-1))*32 + c8*8)*2);
        union { float4 f; unsigned short u[8]; } uu; uu.f = raw;
        float* dst = xs + (row*66 + yy)*33 + c8*8;
#pragma unroll
        for (int jj = 0; jj < 8; ++jj) {
            unsigned int bb = ((unsigned int)uu.u[jj]) << 16;
            float fv; __builtin_memcpy(&fv, &bb, 4);
            dst[jj] = fv;
        }
    }
    __syncthreads();

    const int r4 = t >> 6, whc = t & 63;
    float a0 = bias[0], a1 = bias[1], a2 = bias[2];
#pragma unroll
    for (int rr = 0; rr < 2; ++rr) {
#pragma unroll
        for (int ss = 0; ss < 2; ++ss) {
            const float* wtp = ws + (rr*2+ss)*96;
            const float* xp = xs + ((r4 + ph + rr)*66 + (whc + pw + ss))*33;
#pragma unroll
            for (int c4 = 0; c4 < 8; ++c4) {
                float4 wA = *(const float4*)(wtp + c4*12 + 0);
                float4 wB = *(const float4*)(wtp + c4*12 + 4);
                float4 wC = *(const float4*)(wtp + c4*12 + 8);
                float x0 = xp[4*c4+0], x1 = xp[4*c4+1], x2 = xp[4*c4+2], x3 = xp[4*c4+3];
                a0 = fmaf(x0, wA.x, a0); a1 = fmaf(x0, wA.y, a1); a2 = fmaf(x0, wA.z, a2);
                a0 = fmaf(x1, wA.w, a0); a1 = fmaf(x1, wB.x, a1); a2 = fmaf(x1, wB.y, a2);
                a0 = fmaf(x2, wB.z, a0); a1 = fmaf(x2, wB.w, a1); a2 = fmaf(x2, wC.x, a2);
                a0 = fmaf(x3, wC.y, a0); a1 = fmaf(x3, wC.z, a1); a2 = fmaf(x3, wC.w, a2);
            }
        }
    }
    a0 = 1.0f / (1.0f + __expf(-a0));
    a1 = 1.0f / (1.0f + __expf(-a1));
    a2 = 1.0f / (1.0f + __expf(-a2));
    const int ho = 2*(R0 + r4) + ph, wo = 2*whc + pw;
    float* yp = y + ((size_t)(n*128 + ho)*128 + wo)*3;
    yp[0] = a0; yp[1] = a1; yp[2] = a2;
}

__global__ void zero_loss(float* p) {
    if (threadIdx.x == 0 && blockIdx.x == 0) *p = 0.0f;
}

// ---- VQ (exact fp32 distances; q emitted as bf16) ----
__global__ __launch_bounds__(256) void vq_kernel(
    const float* __restrict__ z, const float* __restrict__ emb,
    __hip_bfloat16* __restrict__ qb, float* __restrict__ idx_out,
    float* __restrict__ loss_out, float loss_scale)
{
    __shared__ float zs[64*65];
    __shared__ float es[64*64];
    __shared__ float gd[4*64];
    __shared__ int   gi[4*64];
    __shared__ float md[64];
    __shared__ int   mi[64];

    const int t = threadIdx.x;
    const int pos0 = blockIdx.x * 64;

    for (int j = t; j < 64*64; j += 256)
        zs[(j >> 6)*65 + (j & 63)] = z[pos0*64 + j];
    __syncthreads();

    const int pos = t & 63;
    const int grp = t >> 6;
    float zr[64];
#pragma unroll
    for (int d = 0; d < 64; ++d) zr[d] = zs[pos*65 + d];

    float bestd = 3.4e38f;
    int   besti = 0;

    for (int ck = 0; ck < 8; ++ck) {
        __syncthreads();
        for (int j = t; j < 4096; j += 256) es[j] = emb[ck*4096 + j];
        __syncthreads();
#pragma unroll
        for (int k = 0; k < 16; ++k) {
            const int cc = grp + 4*k;
            const float4* ep = (const float4*)(es + cc*64);
            float acc = 0.0f;
#pragma unroll
            for (int u = 0; u < 16; ++u) {
                float4 e = ep[u];
                float d0 = zr[4*u+0] - e.x;
                float d1 = zr[4*u+1] - e.y;
                float d2 = zr[4*u+2] - e.z;
                float d3 = zr[4*u+3] - e.w;
                acc = fmaf(d0,d0,acc); acc = fmaf(d1,d1,acc);
                acc = fmaf(d2,d2,acc); acc = fmaf(d3,d3,acc);
            }
            const int code = ck*64 + cc;
            if (acc < bestd) { bestd = acc; besti = code; }
        }
    }
    gd[grp*64 + pos] = bestd;
    gi[grp*64 + pos] = besti;
    __syncthreads();
    if (grp == 0) {
        float bd = gd[pos]; int bi = gi[pos];
#pragma unroll
        for (int g2 = 1; g2 < 4; ++g2) {
            float dv = gd[g2*64 + pos]; int iv = gi[g2*64 + pos];
            if (dv < bd || (dv == bd && iv < bi)) { bd = dv; bi = iv; }
        }
        md[pos] = bd; mi[pos] = bi;
        idx_out[pos0 + pos] = (float)bi;
    }
    __syncthreads();
    for (int j = t; j < 4096; j += 256) {
        int p = j >> 6, d = j & 63;
        qb[pos0*64 + j] = __float2bfloat16(emb[mi[p]*64 + d]);
    }
    if (t == 0) {
        float s = 0.0f;
        for (int p = 0; p < 64; ++p) s += md[p];
        atomicAdd(loss_out, s * loss_scale);
    }
}

extern "C" void kernel_launch(void* const* d_in, const int* in_sizes, int n_in,
                              void* d_out, int out_size, void* d_ws, size_t ws_size,
                              hipStream_t stream)
{
    const float* x   = (const float*)d_in[0];
    const float* ew1 = (const float*)d_in[1];  const float* eb1 = (const float*)d_in[2];
    const float* ew2 = (const float*)d_in[3];  const float* eb2 = (const float*)d_in[4];
    const float* ew3 = (const float*)d_in[5];  const float* eb3 = (const float*)d_in[6];
    const float* ew4 = (const float*)d_in[7];  const float* eb4 = (const float*)d_in[8];
    const float* emb = (const float*)d_in[9];
    const float* dw1 = (const float*)d_in[10]; const float* db1 = (const float*)d_in[11];
    const float* dw2 = (const float*)d_in[12]; const float* db2 = (const float*)d_in[13];
    const float* dw3 = (const float*)d_in[14]; const float* db3 = (const float*)d_in[15];
    const float* dw4 = (const float*)d_in[16]; const float* db4 = (const float*)d_in[17];

    float* outy = (float*)d_out;          // y: 6291456
    float* outl = outy + 6291456;         // loss: 1
    float* outi = outl + 1;               // idx: 32768

    // Workspace layout (time-multiplexed; peak ~119 MB < 134 MB proven):
    char* W = (char*)d_ws;
    float*          e1  = (float*)         (W + 0);          // 16,777,216 el f32 [0,67108864)
    __hip_bfloat16* e2h = (__hip_bfloat16*)(W + 67108864);   // 8,388,608 el
    __hip_bfloat16* e2m = (__hip_bfloat16*)(W + 83886080);
    __hip_bfloat16* e2l = (__hip_bfloat16*)(W + 100663296);  // ends 117440512
    __hip_bfloat16* e3h = (__hip_bfloat16*)(W + 0);          // 4,194,304 el (over dead e1)
    __hip_bfloat16* e3m = (__hip_bfloat16*)(W + 8388608);
    __hip_bfloat16* e3l = (__hip_bfloat16*)(W + 16777216);
    float*          z   = (float*)         (W + 25165824);   // 2,097,152 el f32
    __hip_bfloat16* qb  = (__hip_bfloat16*)(W + 33554432);   // 2,097,152 el
    __hip_bfloat16* d1o = (__hip_bfloat16*)(W + 67108864);   // 4,194,304 el (over dead e2)
    __hip_bfloat16* d2o = (__hip_bfloat16*)(W + 75497472);   // 8,388,608 el
    __hip_bfloat16* d3o = (__hip_bfloat16*)(W + 0);          // 16,777,216 el (over dead e3/z)
    // persistent weights (never overlaid):
    __hip_bfloat16* wh2 = (__hip_bfloat16*)(W + 117440512);  // 32768 el each
    __hip_bfloat16* wm2 = wh2 + 32768;
    __hip_bfloat16* wl2 = wm2 + 32768;
    __hip_bfloat16* wh3 = wl2 + 32768;                       // 131072 el each
    __hip_bfloat16* wm3 = wh3 + 131072;
    __hip_bfloat16* wl3 = wm3 + 131072;
    __hip_bfloat16* wh4 = wl3 + 131072;                      // 32768 el each
    __hip_bfloat16* wm4 = wh4 + 32768;
    __hip_bfloat16* wl4 = wm4 + 32768;
    __hip_bfloat16* wt1 = wl4 + 32768;                       // 32768
    __hip_bfloat16* wt2 = wt1 + 32768;                       // 131072
    __hip_bfloat16* wt3 = wt2 + 131072;                      // 32768

    // ---- weight prep ----
    hipLaunchKernelGGL(prep_wt3, dim3(128), dim3(256), 0, stream, ew2, wh2, wm2, wl2, 16, 32, 64);
    hipLaunchKernelGGL(prep_wt3, dim3(512), dim3(256), 0, stream, ew3, wh3, wm3, wl3, 16, 64, 128);
    hipLaunchKernelGGL(prep_wt3, dim3(128), dim3(256), 0, stream, ew4, wh4, wm4, wl4, 4, 128, 64);
    hipLaunchKernelGGL(prep_wt,  dim3(128), dim3(256), 0, stream, dw1, wt1, 4, 64, 128);
    hipLaunchKernelGGL(prep_wt,  dim3(512), dim3(256), 0, stream, dw2, wt2, 16, 128, 64);
    hipLaunchKernelGGL(prep_wt,  dim3(128), dim3(256), 0, stream, dw3, wt3, 16, 64, 32);

    // ---- encoder (fp32-accurate bf16x3 MFMA) ----
    hipLaunchKernelGGL(enc1_kernel, dim3(1024), dim3(256), 0, stream, x, ew1, eb1, e1);
    hipLaunchKernelGGL((mfma_enc3<4,4,32,64,6,5,2,1,1,1,0,1>), dim3(2048), dim3(256), 0, stream,
                       e1, (const __hip_bfloat16*)nullptr, (const __hip_bfloat16*)nullptr,
                       (const __hip_bfloat16*)nullptr,
                       wh2, wm2, wl2, eb2, e2h, e2m, e2l, (float*)nullptr);
    hipLaunchKernelGGL((mfma_enc3<4,4,64,128,5,4,2,1,1,0,0,2>), dim3(512,2), dim3(256), 0, stream,
                       (const float*)nullptr, e2h, e2m, e2l,
                       wh3, wm3, wl3, eb3, e3h, e3m, e3l, (float*)nullptr);
    hipLaunchKernelGGL((mfma_enc3<2,2,128,64,4,4,1,0,0,0,1,2>), dim3(512,2), dim3(256), 0, stream,
                       (const float*)nullptr, e3h, e3m, e3l,
                       wh4, wm4, wl4, eb4,
                       (__hip_bfloat16*)nullptr, (__hip_bfloat16*)nullptr,
                       (__hip_bfloat16*)nullptr, z);

    // ---- vector quantizer ----
    hipLaunchKernelGGL(zero_loss, dim3(1), dim3(64), 0, stream, outl);
    hipLaunchKernelGGL(vq_kernel, dim3(512), dim3(256), 0, stream,
                       z, emb, qb, outi, outl, 0.25f / 2097152.0f);

    // ---- decoder (bf16 MFMA, validated) ----
    hipLaunchKernelGGL((mfma_dec<64,128,4,0,2>), dim3(512,2),    dim3(256), 0, stream, qb,  wt1, db1, d1o);
    hipLaunchKernelGGL((mfma_dec<128,64,4,1,1>), dim3(512,4),    dim3(256), 0, stream, d1o, wt2, db2, d2o);
    hipLaunchKernelGGL((mfma_dec<64,32,5,1,1>),  dim3(2048,4),   dim3(256), 0, stream, d2o, wt3, db3, d3o);
    hipLaunchKernelGGL(dec4_kernel, dim3(2048,4), dim3(256), 0, stream, d3o, dw4, db4, outy);
}

// Round 8
// 720.357 us; speedup vs baseline: 1.3255x; 1.3255x over previous
//
#include <hip/hip_runtime.h>
#include <hip/hip_bf16.h>

typedef __bf16 bf16x8_t __attribute__((ext_vector_type(8)));
typedef float  f32x4_t  __attribute__((ext_vector_type(4)));

__device__ inline bf16x8_t ld_bf16x8(const __hip_bfloat16* p) {
    return *reinterpret_cast<const bf16x8_t*>(p);
}
__device__ inline bf16x8_t zero_bf16x8() {
    bf16x8_t z;
#pragma unroll
    for (int i = 0; i < 8; ++i) z[i] = (__bf16)0.0f;
    return z;
}

// Exact 3-way bf16 split: v == h + m + l exactly (truncation-based).
__device__ inline void split3f(float v, __bf16& h, __bf16& m, __bf16& l) {
    unsigned u;  __builtin_memcpy(&u, &v, 4);
    unsigned uh = u & 0xffff0000u;
    float fh;    __builtin_memcpy(&fh, &uh, 4);
    float r = v - fh;
    unsigned ur; __builtin_memcpy(&ur, &r, 4);
    unsigned um = ur & 0xffff0000u;
    float fm;    __builtin_memcpy(&fm, &um, 4);
    float r2 = r - fm;
    unsigned ul; __builtin_memcpy(&ul, &r2, 4);
    unsigned short hs = (unsigned short)(uh >> 16);
    unsigned short ms = (unsigned short)(um >> 16);
    unsigned short ls = (unsigned short)(ul >> 16);
    __builtin_memcpy(&h, &hs, 2);
    __builtin_memcpy(&m, &ms, 2);
    __builtin_memcpy(&l, &ls, 2);
}

// ---------------------------------------------------------------------------
// enc1: conv 4x4 s2 pad1, CIN=3, COUT=32, exact fp32 (validated round 3).
// ---------------------------------------------------------------------------
__global__ __launch_bounds__(256) void enc1_kernel(
    const float* __restrict__ x, const float* __restrict__ w,
    const float* __restrict__ bias, float* __restrict__ y)
{
    __shared__ float xs[34*66*3];
    __shared__ float wsm[1536];

    const int n  = blockIdx.x >> 3;
    const int th = (blockIdx.x >> 1) & 3;
    const int tw = blockIdx.x & 1;
    const int HO0 = th*16, WO0 = tw*32;
    const int HI0 = 2*HO0 - 1, WI0 = 2*WO0 - 1;
    const int t = threadIdx.x;

    for (int i = t; i < 1536; i += 256) wsm[i] = w[i];
    for (int i = t; i < 34*66*3; i += 256) {
        int row = i / 198; int j = i - row*198;
        int wi_l = j / 3;  int c = j - wi_l*3;
        int hi = HI0 + row, wi = WI0 + wi_l;
        float v = 0.0f;
        if (hi >= 0 && hi < 128 && wi >= 0 && wi < 128)
            v = x[((n*128 + hi)*128 + wi)*3 + c];
        xs[i] = v;
    }
    __syncthreads();

    const int wl = t & 15, hl = t >> 4;
    float acc0[32], acc1[32];
#pragma unroll
    for (int f4 = 0; f4 < 8; ++f4) {
        float4 bv = *(const float4*)(bias + 4*f4);
        acc0[4*f4+0]=bv.x; acc0[4*f4+1]=bv.y; acc0[4*f4+2]=bv.z; acc0[4*f4+3]=bv.w;
        acc1[4*f4+0]=bv.x; acc1[4*f4+1]=bv.y; acc1[4*f4+2]=bv.z; acc1[4*f4+3]=bv.w;
    }
    for (int r = 0; r < 4; ++r) {
#pragma unroll
        for (int s = 0; s < 4; ++s) {
#pragma unroll
            for (int c = 0; c < 3; ++c) {
                float xv0 = xs[(2*hl + r)*198 + (2*wl + s)*3 + c];
                float xv1 = xs[(2*hl + r)*198 + (2*(wl+16) + s)*3 + c];
                const float* wp = wsm + ((r*4 + s)*3 + c)*32;
#pragma unroll
                for (int f4 = 0; f4 < 8; ++f4) {
                    float4 wv = *(const float4*)(wp + 4*f4);
                    acc0[4*f4+0] = fmaf(xv0, wv.x, acc0[4*f4+0]);
                    acc0[4*f4+1] = fmaf(xv0, wv.y, acc0[4*f4+1]);
                    acc0[4*f4+2] = fmaf(xv0, wv.z, acc0[4*f4+2]);
                    acc0[4*f4+3] = fmaf(xv0, wv.w, acc0[4*f4+3]);
                    acc1[4*f4+0] = fmaf(xv1, wv.x, acc1[4*f4+0]);
                    acc1[4*f4+1] = fmaf(xv1, wv.y, acc1[4*f4+1]);
                    acc1[4*f4+2] = fmaf(xv1, wv.z, acc1[4*f4+2]);
                    acc1[4*f4+3] = fmaf(xv1, wv.w, acc1[4*f4+3]);
                }
            }
        }
    }
    float* y0 = y + ((size_t)((n*64 + HO0 + hl)*64) + WO0 + wl)*32;
#pragma unroll
    for (int f4 = 0; f4 < 8; ++f4) {
        float4 o0 = make_float4(fmaxf(acc0[4*f4+0],0.f), fmaxf(acc0[4*f4+1],0.f),
                                fmaxf(acc0[4*f4+2],0.f), fmaxf(acc0[4*f4+3],0.f));
        *(float4*)(y0 + 4*f4) = o0;
    }
    float* y1 = y0 + 16*32;
#pragma unroll
    for (int f4 = 0; f4 < 8; ++f4) {
        float4 o1 = make_float4(fmaxf(acc1[4*f4+0],0.f), fmaxf(acc1[4*f4+1],0.f),
                                fmaxf(acc1[4*f4+2],0.f), fmaxf(acc1[4*f4+3],0.f));
        *(float4*)(y1 + 4*f4) = o1;
    }
}

// ---------------------------------------------------------------------------
// Weight prep.
//  prep_wt : decoder, [tap][COUT][CIN] bf16.
//  prep_wpk: encoder, exact 3-way split, FRAGMENT-ORDERED for LDS staging:
//            index = ((((tap*3 + plane)*NF + nf)*KC + kc)*64 + lane)*8 + j
//            element = split_plane( w[(tap*CIN + c)*COUT + f] ),
//            f = nf*16 + (lane&15), c = kc*32 + (lane>>4)*8 + j.
// ---------------------------------------------------------------------------
__global__ void prep_wt(const float* __restrict__ w, __hip_bfloat16* __restrict__ wt,
                        int TAPS, int CIN, int COUT)
{
    int i = blockIdx.x*256 + threadIdx.x;
    if (i >= TAPS*CIN*COUT) return;
    int c = i % CIN; int rem = i / CIN;
    int f = rem % COUT; int tap = rem / COUT;
    wt[i] = __float2bfloat16(w[(tap*CIN + c)*COUT + f]);
}

__global__ void prep_wpk(const float* __restrict__ w, __hip_bfloat16* __restrict__ out,
                         int TAPS, int CIN, int COUT)
{
    const int NF = COUT >> 4, KC = CIN >> 5;
    int total = TAPS*3*NF*KC*512;
    int i = blockIdx.x*256 + threadIdx.x;
    if (i >= total) return;
    int tmp = i;
    int j = tmp & 7;      tmp >>= 3;
    int lane = tmp & 63;  tmp >>= 6;
    int kc = tmp % KC;    tmp /= KC;
    int nf = tmp % NF;    tmp /= NF;
    int plane = tmp % 3;  int tap = tmp / 3;
    int l15 = lane & 15, quad = lane >> 4;
    int f = nf*16 + l15;
    int c = kc*32 + quad*8 + j;
    float v = w[(tap*CIN + c)*COUT + f];
    __bf16 h, m, l;
    split3f(v, h, m, l);
    ((__bf16*)out)[i] = (plane == 0) ? h : (plane == 1) ? m : l;
}

// ---------------------------------------------------------------------------
// bf16x3 MFMA encoder conv, B staged per-tap in LDS (frag-ordered,
// conflict-free ds_read_b128). Bit-identical MFMA sequence to round 6.
// INF32: input fp32 [pix][CIN], split on the fly.
// else : input packed bf16 [pix][3][CIN].
// OUTF32: fp32 out (z). else packed bf16 [pix][3][COUT] out (+ReLU if ACT).
// ---------------------------------------------------------------------------
template<int R,int S,int CIN,int COUT,int IWL,int OWL,int STR,int PAD,int ACT,int INF32,int OUTF32>
__global__ __launch_bounds__(256) void mfma_encB(
    const void* __restrict__ xin,
    const __hip_bfloat16* __restrict__ wpk,
    const float* __restrict__ bias,
    __hip_bfloat16* __restrict__ yout,
    float* __restrict__ yf)
{
    constexpr int IW = 1 << IWL, OW = 1 << OWL;
    constexpr int NF = COUT / 16, KC = CIN / 32, TAPS = R*S;
    constexpr int CHUNK8 = 3*NF*KC*64;          // bf16x8 units per tap chunk
    __shared__ bf16x8_t ldsB[CHUNK8];

    const int t = threadIdx.x;
    const int wave = t >> 6, lane = t & 63;
    const int l15 = lane & 15, quad = lane >> 4;

    const int m  = blockIdx.x*64 + wave*16 + l15;
    const int wp_ = m & (OW-1);
    const int hp_ = (m >> OWL) & (OW-1);
    const int np_ = m >> (2*OWL);

    f32x4_t acc[NF];
#pragma unroll
    for (int nf = 0; nf < NF; ++nf) {
        float bv = bias[nf*16 + l15];
        acc[nf][0] = bv; acc[nf][1] = bv; acc[nf][2] = bv; acc[nf][3] = bv;
    }
    const bf16x8_t zv = zero_bf16x8();

    for (int tap = 0; tap < TAPS; ++tap) {
        __syncthreads();
        {
            const bf16x8_t* src = (const bf16x8_t*)wpk + (size_t)tap*CHUNK8;
            for (int i8 = t; i8 < CHUNK8; i8 += 256) ldsB[i8] = src[i8];
        }
        __syncthreads();

        const int r = tap / S, s = tap % S;
        const int hi = hp_*STR - PAD + r;
        const int wi = wp_*STR - PAD + s;
        const bool v = (hi >= 0) && (hi < IW) && (wi >= 0) && (wi < IW);
        const int hic = v ? hi : 0, wic = v ? wi : 0;
        const size_t pix = (size_t)(np_*IW + hic)*IW + wic;

#pragma unroll
        for (int kc = 0; kc < KC; ++kc) {
            bf16x8_t ah, am_, al_;
            if (INF32) {
                const float* af = (const float*)xin + pix*CIN + kc*32 + quad*8;
                float xv[8];
                if (v) {
                    *(float4*)(xv+0) = *(const float4*)(af);
                    *(float4*)(xv+4) = *(const float4*)(af + 4);
                } else {
#pragma unroll
                    for (int jj = 0; jj < 8; ++jj) xv[jj] = 0.0f;
                }
#pragma unroll
                for (int jj = 0; jj < 8; ++jj) {
                    __bf16 th, tm, tl;
                    split3f(xv[jj], th, tm, tl);
                    ah[jj] = th; am_[jj] = tm; al_[jj] = tl;
                }
            } else {
                const __hip_bfloat16* ap = (const __hip_bfloat16*)xin
                    + pix*(3*CIN) + kc*32 + quad*8;
                ah  = v ? ld_bf16x8(ap)           : zv;
                am_ = v ? ld_bf16x8(ap + CIN)     : zv;
                al_ = v ? ld_bf16x8(ap + 2*CIN)   : zv;
            }
#pragma unroll
            for (int nf = 0; nf < NF; ++nf) {
                bf16x8_t bh = ldsB[((0*NF + nf)*KC + kc)*64 + lane];
                bf16x8_t bm = ldsB[((1*NF + nf)*KC + kc)*64 + lane];
                bf16x8_t bl = ldsB[((2*NF + nf)*KC + kc)*64 + lane];
                // small terms first (same order as validated round 6)
                acc[nf] = __builtin_amdgcn_mfma_f32_16x16x32_bf16(al_, bh, acc[nf], 0, 0, 0);
                acc[nf] = __builtin_amdgcn_mfma_f32_16x16x32_bf16(ah,  bl, acc[nf], 0, 0, 0);
                acc[nf] = __builtin_amdgcn_mfma_f32_16x16x32_bf16(am_, bm, acc[nf], 0, 0, 0);
                acc[nf] = __builtin_amdgcn_mfma_f32_16x16x32_bf16(am_, bh, acc[nf], 0, 0, 0);
                acc[nf] = __builtin_amdgcn_mfma_f32_16x16x32_bf16(ah,  bm, acc[nf], 0, 0, 0);
                acc[nf] = __builtin_amdgcn_mfma_f32_16x16x32_bf16(ah,  bh, acc[nf], 0, 0, 0);
            }
        }
    }

#pragma unroll
    for (int nf = 0; nf < NF; ++nf) {
#pragma unroll
        for (int i = 0; i < 4; ++i) {
            int mo = blockIdx.x*64 + wave*16 + quad*4 + i;
            int wo = mo & (OW-1), ho = (mo >> OWL) & (OW-1), no = mo >> (2*OWL);
            size_t opix = (size_t)(no*OW + ho)*OW + wo;
            float vv = acc[nf][i];
            if (ACT) vv = fmaxf(vv, 0.0f);
            if (OUTF32) {
                yf[opix*COUT + nf*16 + l15] = vv;
            } else {
                __bf16 h, mm2, l;
                split3f(vv, h, mm2, l);
                __bf16* yb = (__bf16*)yout + opix*(3*COUT) + nf*16 + l15;
                yb[0]        = h;
                yb[COUT]     = mm2;
                yb[2*COUT]   = l;
            }
        }
    }
}

// ---------------------------------------------------------------------------
// MFMA decoder layer (validated): plain bf16, NSPLIT=1 configs.
// ---------------------------------------------------------------------------
template<int CIN,int COUT,int SWL,int CONVT,int NSPLIT>
__global__ __launch_bounds__(256) void mfma_dec(
    const __hip_bfloat16* __restrict__ xin,
    const __hip_bfloat16* __restrict__ wt,
    const float* __restrict__ bias,
    __hip_bfloat16* __restrict__ yout)
{
    constexpr int SW = 1 << SWL;
    constexpr int NF = COUT / 16 / NSPLIT;
    const int ph = CONVT ? (int)(blockIdx.y >> 1) : 0;
    const int pw = CONVT ? (int)(blockIdx.y & 1) : 0;
    const int nf0 = (CONVT ? (int)blockIdx.z : (int)blockIdx.y) * NF;
    const int t = threadIdx.x;
    const int wave = t >> 6, lane = t & 63;
    const int l15 = lane & 15, quad = lane >> 4;

    const int m  = blockIdx.x*64 + wave*16 + l15;
    const int wp_ = m & (SW-1);
    const int hp_ = (m >> SWL) & (SW-1);
    const int np_ = m >> (2*SWL);

    f32x4_t acc[NF];
#pragma unroll
    for (int nf = 0; nf < NF; ++nf) {
        float bv = bias[(nf0 + nf)*16 + l15];
        acc[nf][0] = bv; acc[nf][1] = bv; acc[nf][2] = bv; acc[nf][3] = bv;
    }
    const bf16x8_t zv = zero_bf16x8();

#pragma unroll
    for (int rr = 0; rr < 2; ++rr) {
#pragma unroll
        for (int ss = 0; ss < 2; ++ss) {
            const int hi = hp_ + ph - 1 + rr;
            const int wi = wp_ + pw - 1 + ss;
            const bool v = (hi >= 0) && (hi < SW) && (wi >= 0) && (wi < SW);
            const int hic = v ? hi : 0, wic = v ? wi : 0;
            const int widx = CONVT ? ((ph + 2*rr)*4 + (pw + 2*ss)) : (rr*2 + ss);
            const __hip_bfloat16* ap = xin + (size_t)((np_*SW + hic)*SW + wic)*CIN + quad*8;
            const __hip_bfloat16* bp = wt + (size_t)(widx*COUT)*CIN + l15*CIN + quad*8;
#pragma unroll
            for (int k0 = 0; k0 < CIN; k0 += 32) {
                bf16x8_t a = v ? ld_bf16x8(ap + k0) : zv;
#pragma unroll
                for (int nf = 0; nf < NF; ++nf) {
                    bf16x8_t b = ld_bf16x8(bp + (size_t)(nf0 + nf)*16*CIN + k0);
                    acc[nf] = __builtin_amdgcn_mfma_f32_16x16x32_bf16(a, b, acc[nf], 0, 0, 0);
                }
            }
        }
    }

    constexpr int HOUT = CONVT ? 2*SW : SW;
#pragma unroll
    for (int nf = 0; nf < NF; ++nf) {
#pragma unroll
        for (int i = 0; i < 4; ++i) {
            int mo = blockIdx.x*64 + wave*16 + quad*4 + i;
            int wo = mo & (SW-1), ho = (mo >> SWL) & (SW-1), no = mo >> (2*SWL);
            int hoo = CONVT ? 2*ho + ph : ho;
            int woo = CONVT ? 2*wo + pw : wo;
            float vv = fmaxf(acc[nf][i], 0.0f);
            yout[((size_t)(no*HOUT + hoo)*HOUT + woo)*COUT + (nf0 + nf)*16 + l15] = __float2bfloat16(vv);
        }
    }
}

// ---------------------------------------------------------------------------
// dec4: convT 4x4 s2, CIN=32 (bf16 in), COUT=3, sigmoid, fp32 math.
// ---------------------------------------------------------------------------
__global__ __launch_bounds__(256) void dec4_kernel(
    const __hip_bfloat16* __restrict__ x, const float* __restrict__ w,
    const float* __restrict__ bias, float* __restrict__ y)
{
    __shared__ float xs[6*66*33];
    __shared__ float ws[4*32*3];

    const int ph = blockIdx.y >> 1, pw = blockIdx.y & 1;
    const int n  = blockIdx.x >> 4;
    const int R0 = (blockIdx.x & 15) * 4;
    const int t  = threadIdx.x;

    if (t < 384) {
        int tap = t / 96, rem = t - tap*96;
        int rr = tap >> 1, ss = tap & 1;
        int gtap = (ph + 2*rr)*4 + (pw + 2*ss);
        ws[t] = w[gtap*96 + rem];
    }
    for (int slot = t; slot < 6*66*4; slot += 256) {
        int row = slot / 264;
        int rem = slot - row*264;
        int yy = rem >> 2, c8 = rem & 3;
        int xi = R0 - 1 + row;
        float4 raw = make_float4(0.f,0.f,0.f,0.f);
        if (yy >= 1 && yy <= 64 && xi >= 0 && xi < 64)
            raw = *(const float4*)((const char*)x + (size_t)((((n*64 + xi)*64) + (yy-1))*32 + c8*8)*2);
        union { float4 f; unsigned short u[8]; } uu; uu.f = raw;
        float* dst = xs + (row*66 + yy)*33 + c8*8;
#pragma unroll
        for (int jj = 0; jj < 8; ++jj) {
            unsigned int bb = ((unsigned int)uu.u[jj]) << 16;
            float fv; __builtin_memcpy(&fv, &bb, 4);
            dst[jj] = fv;
        }
    }
    __syncthreads();

    const int r4 = t >> 6, whc = t & 63;
    float a0 = bias[0], a1 = bias[1], a2 = bias[2];
#pragma unroll
    for (int rr = 0; rr < 2; ++rr) {
#pragma unroll
        for (int ss = 0; ss < 2; ++ss) {
            const float* wtp = ws + (rr*2+ss)*96;
            const float* xp = xs + ((r4 + ph + rr)*66 + (whc + pw + ss))*33;
#pragma unroll
            for (int c4 = 0; c4 < 8; ++c4) {
                float4 wA = *(const float4*)(wtp + c4*12 + 0);
                float4 wB = *(const float4*)(wtp + c4*12 + 4);
                float4 wC = *(const float4*)(wtp + c4*12 + 8);
                float x0 = xp[4*c4+0], x1 = xp[4*c4+1], x2 = xp[4*c4+2], x3 = xp[4*c4+3];
                a0 = fmaf(x0, wA.x, a0); a1 = fmaf(x0, wA.y, a1); a2 = fmaf(x0, wA.z, a2);
                a0 = fmaf(x1, wA.w, a0); a1 = fmaf(x1, wB.x, a1); a2 = fmaf(x1, wB.y, a2);
                a0 = fmaf(x2, wB.z, a0); a1 = fmaf(x2, wB.w, a1); a2 = fmaf(x2, wC.x, a2);
                a0 = fmaf(x3, wC.y, a0); a1 = fmaf(x3, wC.z, a1); a2 = fmaf(x3, wC.w, a2);
            }
        }
    }
    a0 = 1.0f / (1.0f + __expf(-a0));
    a1 = 1.0f / (1.0f + __expf(-a1));
    a2 = 1.0f / (1.0f + __expf(-a2));
    const int ho = 2*(R0 + r4) + ph, wo = 2*whc + pw;
    float* yp = y + ((size_t)(n*128 + ho)*128 + wo)*3;
    yp[0] = a0; yp[1] = a1; yp[2] = a2;
}

__global__ void zero_loss(float* p) {
    if (threadIdx.x == 0 && blockIdx.x == 0) *p = 0.0f;
}

// ---- VQ (exact fp32 distances; q emitted as bf16) ----
__global__ __launch_bounds__(256) void vq_kernel(
    const float* __restrict__ z, const float* __restrict__ emb,
    __hip_bfloat16* __restrict__ qb, float* __restrict__ idx_out,
    float* __restrict__ loss_out, float loss_scale)
{
    __shared__ float zs[64*65];
    __shared__ float es[64*64];
    __shared__ float gd[4*64];
    __shared__ int   gi[4*64];
    __shared__ float md[64];
    __shared__ int   mi[64];

    const int t = threadIdx.x;
    const int pos0 = blockIdx.x * 64;

    for (int j = t; j < 64*64; j += 256)
        zs[(j >> 6)*65 + (j & 63)] = z[pos0*64 + j];
    __syncthreads();

    const int pos = t & 63;
    const int grp = t >> 6;
    float zr[64];
#pragma unroll
    for (int d = 0; d < 64; ++d) zr[d] = zs[pos*65 + d];

    float bestd = 3.4e38f;
    int   besti = 0;

    for (int ck = 0; ck < 8; ++ck) {
        __syncthreads();
        for (int j = t; j < 4096; j += 256) es[j] = emb[ck*4096 + j];
        __syncthreads();
#pragma unroll
        for (int k = 0; k < 16; ++k) {
            const int cc = grp + 4*k;
            const float4* ep = (const float4*)(es + cc*64);
            float acc = 0.0f;
#pragma unroll
            for (int u = 0; u < 16; ++u) {
                float4 e = ep[u];
                float d0 = zr[4*u+0] - e.x;
                float d1 = zr[4*u+1] - e.y;
                float d2 = zr[4*u+2] - e.z;
                float d3 = zr[4*u+3] - e.w;
                acc = fmaf(d0,d0,acc); acc = fmaf(d1,d1,acc);
                acc = fmaf(d2,d2,acc); acc = fmaf(d3,d3,acc);
            }
            const int code = ck*64 + cc;
            if (acc < bestd) { bestd = acc; besti = code; }
        }
    }
    gd[grp*64 + pos] = bestd;
    gi[grp*64 + pos] = besti;
    __syncthreads();
    if (grp == 0) {
        float bd = gd[pos]; int bi = gi[pos];
#pragma unroll
        for (int g2 = 1; g2 < 4; ++g2) {
            float dv = gd[g2*64 + pos]; int iv = gi[g2*64 + pos];
            if (dv < bd || (dv == bd && iv < bi)) { bd = dv; bi = iv; }
        }
        md[pos] = bd; mi[pos] = bi;
        idx_out[pos0 + pos] = (float)bi;
    }
    __syncthreads();
    for (int j = t; j < 4096; j += 256) {
        int p = j >> 6, d = j & 63;
        qb[pos0*64 + j] = __float2bfloat16(emb[mi[p]*64 + d]);
    }
    if (t == 0) {
        float s = 0.0f;
        for (int p = 0; p < 64; ++p) s += md[p];
        atomicAdd(loss_out, s * loss_scale);
    }
}

extern "C" void kernel_launch(void* const* d_in, const int* in_sizes, int n_in,
                              void* d_out, int out_size, void* d_ws, size_t ws_size,
                              hipStream_t stream)
{
    const float* x   = (const float*)d_in[0];
    const float* ew1 = (const float*)d_in[1];  const float* eb1 = (const float*)d_in[2];
    const float* ew2 = (const float*)d_in[3];  const float* eb2 = (const float*)d_in[4];
    const float* ew3 = (const float*)d_in[5];  const float* eb3 = (const float*)d_in[6];
    const float* ew4 = (const float*)d_in[7];  const float* eb4 = (const float*)d_in[8];
    const float* emb = (const float*)d_in[9];
    const float* dw1 = (const float*)d_in[10]; const float* db1 = (const float*)d_in[11];
    const float* dw2 = (const float*)d_in[12]; const float* db2 = (const float*)d_in[13];
    const float* dw3 = (const float*)d_in[14]; const float* db3 = (const float*)d_in[15];
    const float* dw4 = (const float*)d_in[16]; const float* db4 = (const float*)d_in[17];

    float* outy = (float*)d_out;          // y: 6291456
    float* outl = outy + 6291456;         // loss: 1
    float* outi = outl + 1;               // idx: 32768

    // Workspace layout (time-multiplexed; peak < 134,217,728 B proven):
    char* W = (char*)d_ws;
    float*          e1  = (float*)         (W + 0);          // enc1 out fp32, 64 MB [0,67108864)
    __hip_bfloat16* e2p = (__hip_bfloat16*)(W + 67108864);   // enc2 out packed 3-plane, 50.3 MB [..,117440512)
    __hip_bfloat16* e3p = (__hip_bfloat16*)(W + 0);          // enc3 out packed, 25.2 MB (over dead e1)
    float*          z   = (float*)         (W + 25165824);   // 8 MB
    __hip_bfloat16* qb  = (__hip_bfloat16*)(W + 33554432);   // 4 MB
    __hip_bfloat16* d1o = (__hip_bfloat16*)(W + 37748736);   // 8.4 MB
    __hip_bfloat16* d2o = (__hip_bfloat16*)(W + 46137344);   // 16.8 MB (ends 62914560 < 67108864)
    __hip_bfloat16* d3o = (__hip_bfloat16*)(W + 67108864);   // 33.6 MB (over dead e2p)
    // persistent weights:
    __hip_bfloat16* wp2 = (__hip_bfloat16*)(W + 117440512);  // 16*3*4*1*512 =  98304 el
    __hip_bfloat16* wp3 = wp2 + 98304;                       // 16*3*8*2*512 = 393216 el
    __hip_bfloat16* wp4 = wp3 + 393216;                      //  4*3*4*4*512 =  98304 el
    __hip_bfloat16* wt1 = wp4 + 98304;                       // 32768
    __hip_bfloat16* wt2 = wt1 + 32768;                       // 131072
    __hip_bfloat16* wt3 = wt2 + 131072;                      // 32768

    // ---- weight prep ----
    hipLaunchKernelGGL(prep_wpk, dim3(384),  dim3(256), 0, stream, ew2, wp2, 16, 32, 64);
    hipLaunchKernelGGL(prep_wpk, dim3(1536), dim3(256), 0, stream, ew3, wp3, 16, 64, 128);
    hipLaunchKernelGGL(prep_wpk, dim3(384),  dim3(256), 0, stream, ew4, wp4, 4, 128, 64);
    hipLaunchKernelGGL(prep_wt,  dim3(128),  dim3(256), 0, stream, dw1, wt1, 4, 64, 128);
    hipLaunchKernelGGL(prep_wt,  dim3(512),  dim3(256), 0, stream, dw2, wt2, 16, 128, 64);
    hipLaunchKernelGGL(prep_wt,  dim3(128),  dim3(256), 0, stream, dw3, wt3, 16, 64, 32);

    // ---- encoder (fp32-accurate bf16x3 MFMA, B in LDS) ----
    hipLaunchKernelGGL(enc1_kernel, dim3(1024), dim3(256), 0, stream, x, ew1, eb1, e1);
    hipLaunchKernelGGL((mfma_encB<4,4,32,64,6,5,2,1,1,1,0>), dim3(2048), dim3(256), 0, stream,
                       (const void*)e1, wp2, eb2, e2p, (float*)nullptr);
    hipLaunchKernelGGL((mfma_encB<4,4,64,128,5,4,2,1,1,0,0>), dim3(512), dim3(256), 0, stream,
                       (const void*)e2p, wp3, eb3, e3p, (float*)nullptr);
    hipLaunchKernelGGL((mfma_encB<2,2,128,64,4,4,1,0,0,0,1>), dim3(512), dim3(256), 0, stream,
                       (const void*)e3p, wp4, eb4, (__hip_bfloat16*)nullptr, z);

    // ---- vector quantizer ----
    hipLaunchKernelGGL(zero_loss, dim3(1), dim3(64), 0, stream, outl);
    hipLaunchKernelGGL(vq_kernel, dim3(512), dim3(256), 0, stream,
                       z, emb, qb, outi, outl, 0.25f / 2097152.0f);

    // ---- decoder (bf16 MFMA, validated round-6 configs) ----
    hipLaunchKernelGGL((mfma_dec<64,128,4,0,1>), dim3(512,1),  dim3(256), 0, stream, qb,  wt1, db1, d1o);
    hipLaunchKernelGGL((mfma_dec<128,64,4,1,1>), dim3(512,4),  dim3(256), 0, stream, d1o, wt2, db2, d2o);
    hipLaunchKernelGGL((mfma_dec<64,32,5,1,1>),  dim3(2048,4), dim3(256), 0, stream, d2o, wt3, db3, d3o);
    hipLaunchKernelGGL(dec4_kernel, dim3(2048,4), dim3(256), 0, stream, d3o, dw4, db4, outy);
}

// Round 9
// 527.458 us; speedup vs baseline: 1.8103x; 1.3657x over previous
//
#include <hip/hip_runtime.h>
#include <hip/hip_bf16.h>

typedef __bf16 bf16x8_t __attribute__((ext_vector_type(8)));
typedef float  f32x4_t  __attribute__((ext_vector_type(4)));

__device__ inline bf16x8_t ld_bf16x8(const __hip_bfloat16* p) {
    return *reinterpret_cast<const bf16x8_t*>(p);
}
__device__ inline bf16x8_t zero_bf16x8() {
    bf16x8_t z;
#pragma unroll
    for (int i = 0; i < 8; ++i) z[i] = (__bf16)0.0f;
    return z;
}

// Exact 3-way bf16 split: v == h + m + l exactly (truncation-based).
__device__ inline void split3f(float v, __bf16& h, __bf16& m, __bf16& l) {
    unsigned u;  __builtin_memcpy(&u, &v, 4);
    unsigned uh = u & 0xffff0000u;
    float fh;    __builtin_memcpy(&fh, &uh, 4);
    float r = v - fh;
    unsigned ur; __builtin_memcpy(&ur, &r, 4);
    unsigned um = ur & 0xffff0000u;
    float fm;    __builtin_memcpy(&fm, &um, 4);
    float r2 = r - fm;
    unsigned ul; __builtin_memcpy(&ul, &r2, 4);
    unsigned short hs = (unsigned short)(uh >> 16);
    unsigned short ms = (unsigned short)(um >> 16);
    unsigned short ls = (unsigned short)(ul >> 16);
    __builtin_memcpy(&h, &hs, 2);
    __builtin_memcpy(&m, &ms, 2);
    __builtin_memcpy(&l, &ls, 2);
}

// ---------------------------------------------------------------------------
// enc1: conv 4x4 s2 pad1, CIN=3, COUT=32, exact fp32 (validated).
// ---------------------------------------------------------------------------
__global__ __launch_bounds__(256) void enc1_kernel(
    const float* __restrict__ x, const float* __restrict__ w,
    const float* __restrict__ bias, float* __restrict__ y)
{
    __shared__ float xs[34*66*3];
    __shared__ float wsm[1536];

    const int n  = blockIdx.x >> 3;
    const int th = (blockIdx.x >> 1) & 3;
    const int tw = blockIdx.x & 1;
    const int HO0 = th*16, WO0 = tw*32;
    const int HI0 = 2*HO0 - 1, WI0 = 2*WO0 - 1;
    const int t = threadIdx.x;

    for (int i = t; i < 1536; i += 256) wsm[i] = w[i];
    for (int i = t; i < 34*66*3; i += 256) {
        int row = i / 198; int j = i - row*198;
        int wi_l = j / 3;  int c = j - wi_l*3;
        int hi = HI0 + row, wi = WI0 + wi_l;
        float v = 0.0f;
        if (hi >= 0 && hi < 128 && wi >= 0 && wi < 128)
            v = x[((n*128 + hi)*128 + wi)*3 + c];
        xs[i] = v;
    }
    __syncthreads();

    const int wl = t & 15, hl = t >> 4;
    float acc0[32], acc1[32];
#pragma unroll
    for (int f4 = 0; f4 < 8; ++f4) {
        float4 bv = *(const float4*)(bias + 4*f4);
        acc0[4*f4+0]=bv.x; acc0[4*f4+1]=bv.y; acc0[4*f4+2]=bv.z; acc0[4*f4+3]=bv.w;
        acc1[4*f4+0]=bv.x; acc1[4*f4+1]=bv.y; acc1[4*f4+2]=bv.z; acc1[4*f4+3]=bv.w;
    }
    for (int r = 0; r < 4; ++r) {
#pragma unroll
        for (int s = 0; s < 4; ++s) {
#pragma unroll
            for (int c = 0; c < 3; ++c) {
                float xv0 = xs[(2*hl + r)*198 + (2*wl + s)*3 + c];
                float xv1 = xs[(2*hl + r)*198 + (2*(wl+16) + s)*3 + c];
                const float* wp = wsm + ((r*4 + s)*3 + c)*32;
#pragma unroll
                for (int f4 = 0; f4 < 8; ++f4) {
                    float4 wv = *(const float4*)(wp + 4*f4);
                    acc0[4*f4+0] = fmaf(xv0, wv.x, acc0[4*f4+0]);
                    acc0[4*f4+1] = fmaf(xv0, wv.y, acc0[4*f4+1]);
                    acc0[4*f4+2] = fmaf(xv0, wv.z, acc0[4*f4+2]);
                    acc0[4*f4+3] = fmaf(xv0, wv.w, acc0[4*f4+3]);
                    acc1[4*f4+0] = fmaf(xv1, wv.x, acc1[4*f4+0]);
                    acc1[4*f4+1] = fmaf(xv1, wv.y, acc1[4*f4+1]);
                    acc1[4*f4+2] = fmaf(xv1, wv.z, acc1[4*f4+2]);
                    acc1[4*f4+3] = fmaf(xv1, wv.w, acc1[4*f4+3]);
                }
            }
        }
    }
    float* y0 = y + ((size_t)((n*64 + HO0 + hl)*64) + WO0 + wl)*32;
#pragma unroll
    for (int f4 = 0; f4 < 8; ++f4) {
        float4 o0 = make_float4(fmaxf(acc0[4*f4+0],0.f), fmaxf(acc0[4*f4+1],0.f),
                                fmaxf(acc0[4*f4+2],0.f), fmaxf(acc0[4*f4+3],0.f));
        *(float4*)(y0 + 4*f4) = o0;
    }
    float* y1 = y0 + 16*32;
#pragma unroll
    for (int f4 = 0; f4 < 8; ++f4) {
        float4 o1 = make_float4(fmaxf(acc1[4*f4+0],0.f), fmaxf(acc1[4*f4+1],0.f),
                                fmaxf(acc1[4*f4+2],0.f), fmaxf(acc1[4*f4+3],0.f));
        *(float4*)(y1 + 4*f4) = o1;
    }
}

// ---------------------------------------------------------------------------
// Weight prep.
//  prep_wpk: encoder, exact 3-way split, fragment-ordered (validated r8).
//  prep_wdk: decoder, single bf16 plane, fragment-ordered:
//            idx = (((tap*NF + nf)*KC + kc)*64 + lane)*8 + j
//  prep_wb4: dec4 B-fragments [gtap][lane][8], COUT padded 3->16 w/ zeros.
// ---------------------------------------------------------------------------
__global__ void prep_wpk(const float* __restrict__ w, __hip_bfloat16* __restrict__ out,
                         int TAPS, int CIN, int COUT)
{
    const int NF = COUT >> 4, KC = CIN >> 5;
    int total = TAPS*3*NF*KC*512;
    int i = blockIdx.x*256 + threadIdx.x;
    if (i >= total) return;
    int tmp = i;
    int j = tmp & 7;      tmp >>= 3;
    int lane = tmp & 63;  tmp >>= 6;
    int kc = tmp % KC;    tmp /= KC;
    int nf = tmp % NF;    tmp /= NF;
    int plane = tmp % 3;  int tap = tmp / 3;
    int l15 = lane & 15, quad = lane >> 4;
    int f = nf*16 + l15;
    int c = kc*32 + quad*8 + j;
    float v = w[(tap*CIN + c)*COUT + f];
    __bf16 h, m, l;
    split3f(v, h, m, l);
    ((__bf16*)out)[i] = (plane == 0) ? h : (plane == 1) ? m : l;
}

__global__ void prep_wdk(const float* __restrict__ w, __hip_bfloat16* __restrict__ out,
                         int TAPS, int CIN, int COUT)
{
    const int NF = COUT >> 4, KC = CIN >> 5;
    int total = TAPS*NF*KC*512;
    int i = blockIdx.x*256 + threadIdx.x;
    if (i >= total) return;
    int tmp = i;
    int j = tmp & 7;      tmp >>= 3;
    int lane = tmp & 63;  tmp >>= 6;
    int kc = tmp % KC;    tmp /= KC;
    int nf = tmp % NF;    tmp /= NF;
    int tap = tmp;
    int l15 = lane & 15, quad = lane >> 4;
    int f = nf*16 + l15;
    int c = kc*32 + quad*8 + j;
    out[i] = __float2bfloat16(w[(tap*CIN + c)*COUT + f]);
}

__global__ void prep_wb4(const float* __restrict__ w, __hip_bfloat16* __restrict__ out)
{
    int i = blockIdx.x*256 + threadIdx.x;
    if (i >= 16*64*8) return;
    int j = i & 7;
    int lane = (i >> 3) & 63;
    int g = i >> 9;
    int f = lane & 15;
    int c = (lane >> 4)*8 + j;
    float v = (f < 3) ? w[g*96 + c*3 + f] : 0.0f;
    out[i] = __float2bfloat16(v);
}

// ---------------------------------------------------------------------------
// bf16x3 MFMA encoder conv, B staged per-tap in LDS (validated r8).
// ---------------------------------------------------------------------------
template<int R,int S,int CIN,int COUT,int IWL,int OWL,int STR,int PAD,int ACT,int INF32,int OUTF32>
__global__ __launch_bounds__(256) void mfma_encB(
    const void* __restrict__ xin,
    const __hip_bfloat16* __restrict__ wpk,
    const float* __restrict__ bias,
    __hip_bfloat16* __restrict__ yout,
    float* __restrict__ yf)
{
    constexpr int IW = 1 << IWL, OW = 1 << OWL;
    constexpr int NF = COUT / 16, KC = CIN / 32, TAPS = R*S;
    constexpr int CHUNK8 = 3*NF*KC*64;
    __shared__ bf16x8_t ldsB[CHUNK8];

    const int t = threadIdx.x;
    const int wave = t >> 6, lane = t & 63;
    const int l15 = lane & 15, quad = lane >> 4;

    const int m  = blockIdx.x*64 + wave*16 + l15;
    const int wp_ = m & (OW-1);
    const int hp_ = (m >> OWL) & (OW-1);
    const int np_ = m >> (2*OWL);

    f32x4_t acc[NF];
#pragma unroll
    for (int nf = 0; nf < NF; ++nf) {
        float bv = bias[nf*16 + l15];
        acc[nf][0] = bv; acc[nf][1] = bv; acc[nf][2] = bv; acc[nf][3] = bv;
    }
    const bf16x8_t zv = zero_bf16x8();

    for (int tap = 0; tap < TAPS; ++tap) {
        __syncthreads();
        {
            const bf16x8_t* src = (const bf16x8_t*)wpk + (size_t)tap*CHUNK8;
            for (int i8 = t; i8 < CHUNK8; i8 += 256) ldsB[i8] = src[i8];
        }
        __syncthreads();

        const int r = tap / S, s = tap % S;
        const int hi = hp_*STR - PAD + r;
        const int wi = wp_*STR - PAD + s;
        const bool v = (hi >= 0) && (hi < IW) && (wi >= 0) && (wi < IW);
        const int hic = v ? hi : 0, wic = v ? wi : 0;
        const size_t pix = (size_t)(np_*IW + hic)*IW + wic;

#pragma unroll
        for (int kc = 0; kc < KC; ++kc) {
            bf16x8_t ah, am_, al_;
            if (INF32) {
                const float* af = (const float*)xin + pix*CIN + kc*32 + quad*8;
                float xv[8];
                if (v) {
                    *(float4*)(xv+0) = *(const float4*)(af);
                    *(float4*)(xv+4) = *(const float4*)(af + 4);
                } else {
#pragma unroll
                    for (int jj = 0; jj < 8; ++jj) xv[jj] = 0.0f;
                }
#pragma unroll
                for (int jj = 0; jj < 8; ++jj) {
                    __bf16 th, tm, tl;
                    split3f(xv[jj], th, tm, tl);
                    ah[jj] = th; am_[jj] = tm; al_[jj] = tl;
                }
            } else {
                const __hip_bfloat16* ap = (const __hip_bfloat16*)xin
                    + pix*(3*CIN) + kc*32 + quad*8;
                ah  = v ? ld_bf16x8(ap)           : zv;
                am_ = v ? ld_bf16x8(ap + CIN)     : zv;
                al_ = v ? ld_bf16x8(ap + 2*CIN)   : zv;
            }
#pragma unroll
            for (int nf = 0; nf < NF; ++nf) {
                bf16x8_t bh = ldsB[((0*NF + nf)*KC + kc)*64 + lane];
                bf16x8_t bm = ldsB[((1*NF + nf)*KC + kc)*64 + lane];
                bf16x8_t bl = ldsB[((2*NF + nf)*KC + kc)*64 + lane];
                acc[nf] = __builtin_amdgcn_mfma_f32_16x16x32_bf16(al_, bh, acc[nf], 0, 0, 0);
                acc[nf] = __builtin_amdgcn_mfma_f32_16x16x32_bf16(ah,  bl, acc[nf], 0, 0, 0);
                acc[nf] = __builtin_amdgcn_mfma_f32_16x16x32_bf16(am_, bm, acc[nf], 0, 0, 0);
                acc[nf] = __builtin_amdgcn_mfma_f32_16x16x32_bf16(am_, bh, acc[nf], 0, 0, 0);
                acc[nf] = __builtin_amdgcn_mfma_f32_16x16x32_bf16(ah,  bm, acc[nf], 0, 0, 0);
                acc[nf] = __builtin_amdgcn_mfma_f32_16x16x32_bf16(ah,  bh, acc[nf], 0, 0, 0);
            }
        }
    }

#pragma unroll
    for (int nf = 0; nf < NF; ++nf) {
#pragma unroll
        for (int i = 0; i < 4; ++i) {
            int mo = blockIdx.x*64 + wave*16 + quad*4 + i;
            int wo = mo & (OW-1), ho = (mo >> OWL) & (OW-1), no = mo >> (2*OWL);
            size_t opix = (size_t)(no*OW + ho)*OW + wo;
            float vv = acc[nf][i];
            if (ACT) vv = fmaxf(vv, 0.0f);
            if (OUTF32) {
                yf[opix*COUT + nf*16 + l15] = vv;
            } else {
                __bf16 h, mm2, l;
                split3f(vv, h, mm2, l);
                __bf16* yb = (__bf16*)yout + opix*(3*COUT) + nf*16 + l15;
                yb[0]        = h;
                yb[COUT]     = mm2;
                yb[2*COUT]   = l;
            }
        }
    }
}

// ---------------------------------------------------------------------------
// MFMA decoder layer, B staged per-tap in LDS (frag-ordered wdk).
// Same math/epilogue as validated mfma_dec; only B path changed.
// ---------------------------------------------------------------------------
template<int CIN,int COUT,int SWL,int CONVT>
__global__ __launch_bounds__(256) void mfma_decB(
    const __hip_bfloat16* __restrict__ xin,
    const __hip_bfloat16* __restrict__ wdk,
    const float* __restrict__ bias,
    __hip_bfloat16* __restrict__ yout)
{
    constexpr int SW = 1 << SWL;
    constexpr int NF = COUT / 16, KC = CIN / 32;
    constexpr int CHUNK8 = NF*KC*64;
    __shared__ bf16x8_t ldsB[CHUNK8];

    const int ph = CONVT ? (int)(blockIdx.y >> 1) : 0;
    const int pw = CONVT ? (int)(blockIdx.y & 1) : 0;
    const int t = threadIdx.x;
    const int wave = t >> 6, lane = t & 63;
    const int l15 = lane & 15, quad = lane >> 4;

    const int m  = blockIdx.x*64 + wave*16 + l15;
    const int wp_ = m & (SW-1);
    const int hp_ = (m >> SWL) & (SW-1);
    const int np_ = m >> (2*SWL);

    f32x4_t acc[NF];
#pragma unroll
    for (int nf = 0; nf < NF; ++nf) {
        float bv = bias[nf*16 + l15];
        acc[nf][0] = bv; acc[nf][1] = bv; acc[nf][2] = bv; acc[nf][3] = bv;
    }
    const bf16x8_t zv = zero_bf16x8();

    for (int tap = 0; tap < 4; ++tap) {
        const int rr = tap >> 1, ss = tap & 1;
        const int widx = CONVT ? ((ph + 2*rr)*4 + (pw + 2*ss)) : tap;
        __syncthreads();
        {
            const bf16x8_t* src = (const bf16x8_t*)wdk + (size_t)widx*CHUNK8;
            for (int i8 = t; i8 < CHUNK8; i8 += 256) ldsB[i8] = src[i8];
        }
        __syncthreads();

        const int hi = hp_ + ph - 1 + rr;
        const int wi = wp_ + pw - 1 + ss;
        const bool v = (hi >= 0) && (hi < SW) && (wi >= 0) && (wi < SW);
        const int hic = v ? hi : 0, wic = v ? wi : 0;
        const __hip_bfloat16* ap = xin + (size_t)((np_*SW + hic)*SW + wic)*CIN + quad*8;
#pragma unroll
        for (int kc = 0; kc < KC; ++kc) {
            bf16x8_t a = v ? ld_bf16x8(ap + kc*32) : zv;
#pragma unroll
            for (int nf = 0; nf < NF; ++nf) {
                bf16x8_t b = ldsB[(nf*KC + kc)*64 + lane];
                acc[nf] = __builtin_amdgcn_mfma_f32_16x16x32_bf16(a, b, acc[nf], 0, 0, 0);
            }
        }
    }

    constexpr int HOUT = CONVT ? 2*SW : SW;
#pragma unroll
    for (int nf = 0; nf < NF; ++nf) {
#pragma unroll
        for (int i = 0; i < 4; ++i) {
            int mo = blockIdx.x*64 + wave*16 + quad*4 + i;
            int wo = mo & (SW-1), ho = (mo >> SWL) & (SW-1), no = mo >> (2*SWL);
            int hoo = CONVT ? 2*ho + ph : ho;
            int woo = CONVT ? 2*wo + pw : wo;
            float vv = fmaxf(acc[nf][i], 0.0f);
            yout[((size_t)(no*HOUT + hoo)*HOUT + woo)*COUT + nf*16 + l15] = __float2bfloat16(vv);
        }
    }
}

// ---------------------------------------------------------------------------
// dec4 via MFMA: convT 4x4 s2, CIN=32, COUT=3 (padded to 16 in B), sigmoid.
// Block = 4 input rows x 64 cols; tile staged ONCE for all 4 parities.
// Weights: 16 tap-fragments in VGPRs (wb4). 9 LDS A-frags feed 16 MFMAs/row.
// LDS pixel stride 40 elements (80 B): 16B-aligned b128, <=2-way banks.
// ---------------------------------------------------------------------------
__global__ __launch_bounds__(256) void dec4_mfma(
    const __hip_bfloat16* __restrict__ x, const __hip_bfloat16* __restrict__ wb,
    const float* __restrict__ bias, float* __restrict__ y)
{
    __shared__ __hip_bfloat16 xs[6*66*40];   // 31680 B

    const int n  = blockIdx.x >> 4;
    const int R0 = (blockIdx.x & 15) * 4;
    const int t  = threadIdx.x;
    const int wave = t >> 6, lane = t & 63;
    const int l15 = lane & 15, quad = lane >> 4;

    bf16x8_t wreg[16];
#pragma unroll
    for (int g = 0; g < 16; ++g)
        wreg[g] = ld_bf16x8(wb + (size_t)(g*64 + lane)*8);

    const float bv = (l15 < 3) ? bias[l15] : 0.0f;

    for (int slot = t; slot < 6*66*4; slot += 256) {
        int row = slot / 264;
        int rem = slot - row*264;
        int col = rem >> 2, c8 = rem & 3;
        int xi = R0 - 1 + row, xc = col - 1;
        uint4 val = make_uint4(0u,0u,0u,0u);
        if (xi >= 0 && xi < 64 && xc >= 0 && xc < 64)
            val = *(const uint4*)(x + ((size_t)((n*64 + xi)*64) + xc)*32 + c8*8);
        *(uint4*)(xs + (row*66 + col)*40 + c8*8) = val;
    }
    __syncthreads();

    for (int r4 = 0; r4 < 4; ++r4) {
        bf16x8_t af[3][3];
#pragma unroll
        for (int dr = 0; dr < 3; ++dr)
#pragma unroll
            for (int dc = 0; dc < 3; ++dc)
                af[dr][dc] = *(const bf16x8_t*)(xs
                    + ((r4 + dr)*66 + (wave*16 + l15 + dc))*40 + quad*8);

#pragma unroll
        for (int ph = 0; ph < 2; ++ph)
#pragma unroll
        for (int pw = 0; pw < 2; ++pw) {
            f32x4_t acc;
            acc[0] = bv; acc[1] = bv; acc[2] = bv; acc[3] = bv;
#pragma unroll
            for (int rr = 0; rr < 2; ++rr)
#pragma unroll
            for (int ss = 0; ss < 2; ++ss) {
                const int g = (ph + 2*rr)*4 + (pw + 2*ss);
                acc = __builtin_amdgcn_mfma_f32_16x16x32_bf16(
                          af[ph+rr][pw+ss], wreg[g], acc, 0, 0, 0);
            }
            if (l15 < 3) {
#pragma unroll
                for (int i = 0; i < 4; ++i) {
                    int pc = wave*16 + quad*4 + i;
                    int ho = 2*(R0 + r4) + ph, wo = 2*pc + pw;
                    float vv = 1.0f / (1.0f + __expf(-acc[i]));
                    y[((size_t)(n*128 + ho)*128 + wo)*3 + l15] = vv;
                }
            }
        }
    }
}

__global__ void zero_loss(float* p) {
    if (threadIdx.x == 0 && blockIdx.x == 0) *p = 0.0f;
}

// ---- VQ (exact fp32 distances; q emitted as bf16) ----
__global__ __launch_bounds__(256) void vq_kernel(
    const float* __restrict__ z, const float* __restrict__ emb,
    __hip_bfloat16* __restrict__ qb, float* __restrict__ idx_out,
    float* __restrict__ loss_out, float loss_scale)
{
    __shared__ float zs[64*65];
    __shared__ float es[64*64];
    __shared__ float gd[4*64];
    __shared__ int   gi[4*64];
    __shared__ float md[64];
    __shared__ int   mi[64];

    const int t = threadIdx.x;
    const int pos0 = blockIdx.x * 64;

    for (int j = t; j < 64*64; j += 256)
        zs[(j >> 6)*65 + (j & 63)] = z[pos0*64 + j];
    __syncthreads();

    const int pos = t & 63;
    const int grp = t >> 6;
    float zr[64];
#pragma unroll
    for (int d = 0; d < 64; ++d) zr[d] = zs[pos*65 + d];

    float bestd = 3.4e38f;
    int   besti = 0;

    for (int ck = 0; ck < 8; ++ck) {
        __syncthreads();
        for (int j = t; j < 4096; j += 256) es[j] = emb[ck*4096 + j];
        __syncthreads();
#pragma unroll
        for (int k = 0; k < 16; ++k) {
            const int cc = grp + 4*k;
            const float4* ep = (const float4*)(es + cc*64);
            float acc = 0.0f;
#pragma unroll
            for (int u = 0; u < 16; ++u) {
                float4 e = ep[u];
                float d0 = zr[4*u+0] - e.x;
                float d1 = zr[4*u+1] - e.y;
                float d2 = zr[4*u+2] - e.z;
                float d3 = zr[4*u+3] - e.w;
                acc = fmaf(d0,d0,acc); acc = fmaf(d1,d1,acc);
                acc = fmaf(d2,d2,acc); acc = fmaf(d3,d3,acc);
            }
            const int code = ck*64 + cc;
            if (acc < bestd) { bestd = acc; besti = code; }
        }
    }
    gd[grp*64 + pos] = bestd;
    gi[grp*64 + pos] = besti;
    __syncthreads();
    if (grp == 0) {
        float bd = gd[pos]; int bi = gi[pos];
#pragma unroll
        for (int g2 = 1; g2 < 4; ++g2) {
            float dv = gd[g2*64 + pos]; int iv = gi[g2*64 + pos];
            if (dv < bd || (dv == bd && iv < bi)) { bd = dv; bi = iv; }
        }
        md[pos] = bd; mi[pos] = bi;
        idx_out[pos0 + pos] = (float)bi;
    }
    __syncthreads();
    for (int j = t; j < 4096; j += 256) {
        int p = j >> 6, d = j & 63;
        qb[pos0*64 + j] = __float2bfloat16(emb[mi[p]*64 + d]);
    }
    if (t == 0) {
        float s = 0.0f;
        for (int p = 0; p < 64; ++p) s += md[p];
        atomicAdd(loss_out, s * loss_scale);
    }
}

extern "C" void kernel_launch(void* const* d_in, const int* in_sizes, int n_in,
                              void* d_out, int out_size, void* d_ws, size_t ws_size,
                              hipStream_t stream)
{
    const float* x   = (const float*)d_in[0];
    const float* ew1 = (const float*)d_in[1];  const float* eb1 = (const float*)d_in[2];
    const float* ew2 = (const float*)d_in[3];  const float* eb2 = (const float*)d_in[4];
    const float* ew3 = (const float*)d_in[5];  const float* eb3 = (const float*)d_in[6];
    const float* ew4 = (const float*)d_in[7];  const float* eb4 = (const float*)d_in[8];
    const float* emb = (const float*)d_in[9];
    const float* dw1 = (const float*)d_in[10]; const float* db1 = (const float*)d_in[11];
    const float* dw2 = (const float*)d_in[12]; const float* db2 = (const float*)d_in[13];
    const float* dw3 = (const float*)d_in[14]; const float* db3 = (const float*)d_in[15];
    const float* dw4 = (const float*)d_in[16]; const float* db4 = (const float*)d_in[17];

    float* outy = (float*)d_out;          // y: 6291456
    float* outl = outy + 6291456;         // loss: 1
    float* outi = outl + 1;               // idx: 32768

    // Workspace layout (time-multiplexed; peak < 134,217,728 B):
    char* W = (char*)d_ws;
    float*          e1  = (float*)         (W + 0);          // 64 MB [0,67108864)
    __hip_bfloat16* e2p = (__hip_bfloat16*)(W + 67108864);   // 50.3 MB
    __hip_bfloat16* e3p = (__hip_bfloat16*)(W + 0);          // 25.2 MB (over dead e1)
    float*          z   = (float*)         (W + 25165824);   // 8 MB
    __hip_bfloat16* qb  = (__hip_bfloat16*)(W + 33554432);   // 4 MB
    __hip_bfloat16* d1o = (__hip_bfloat16*)(W + 37748736);   // 8.4 MB
    __hip_bfloat16* d2o = (__hip_bfloat16*)(W + 46137344);   // 16.8 MB
    __hip_bfloat16* d3o = (__hip_bfloat16*)(W + 67108864);   // 33.6 MB (over dead e2p)
    // persistent weights:
    __hip_bfloat16* wp2 = (__hip_bfloat16*)(W + 117440512);  //  98304 el
    __hip_bfloat16* wp3 = wp2 + 98304;                       // 393216 el
    __hip_bfloat16* wp4 = wp3 + 393216;                      //  98304 el
    __hip_bfloat16* wd1 = wp4 + 98304;                       //  32768 el
    __hip_bfloat16* wd2 = wd1 + 32768;                       // 131072 el
    __hip_bfloat16* wd3 = wd2 + 131072;                      //  32768 el
    __hip_bfloat16* wb4 = wd3 + 32768;                       //   8192 el

    // ---- weight prep ----
    hipLaunchKernelGGL(prep_wpk, dim3(384),  dim3(256), 0, stream, ew2, wp2, 16, 32, 64);
    hipLaunchKernelGGL(prep_wpk, dim3(1536), dim3(256), 0, stream, ew3, wp3, 16, 64, 128);
    hipLaunchKernelGGL(prep_wpk, dim3(384),  dim3(256), 0, stream, ew4, wp4, 4, 128, 64);
    hipLaunchKernelGGL(prep_wdk, dim3(128),  dim3(256), 0, stream, dw1, wd1, 4, 64, 128);
    hipLaunchKernelGGL(prep_wdk, dim3(512),  dim3(256), 0, stream, dw2, wd2, 16, 128, 64);
    hipLaunchKernelGGL(prep_wdk, dim3(128),  dim3(256), 0, stream, dw3, wd3, 16, 64, 32);
    hipLaunchKernelGGL(prep_wb4, dim3(32),   dim3(256), 0, stream, dw4, wb4);

    // ---- encoder (fp32-accurate bf16x3 MFMA, B in LDS; validated) ----
    hipLaunchKernelGGL(enc1_kernel, dim3(1024), dim3(256), 0, stream, x, ew1, eb1, e1);
    hipLaunchKernelGGL((mfma_encB<4,4,32,64,6,5,2,1,1,1,0>), dim3(2048), dim3(256), 0, stream,
                       (const void*)e1, wp2, eb2, e2p, (float*)nullptr);
    hipLaunchKernelGGL((mfma_encB<4,4,64,128,5,4,2,1,1,0,0>), dim3(512), dim3(256), 0, stream,
                       (const void*)e2p, wp3, eb3, e3p, (float*)nullptr);
    hipLaunchKernelGGL((mfma_encB<2,2,128,64,4,4,1,0,0,0,1>), dim3(512), dim3(256), 0, stream,
                       (const void*)e3p, wp4, eb4, (__hip_bfloat16*)nullptr, z);

    // ---- vector quantizer ----
    hipLaunchKernelGGL(zero_loss, dim3(1), dim3(64), 0, stream, outl);
    hipLaunchKernelGGL(vq_kernel, dim3(512), dim3(256), 0, stream,
                       z, emb, qb, outi, outl, 0.25f / 2097152.0f);

    // ---- decoder (bf16 MFMA, B in LDS) ----
    hipLaunchKernelGGL((mfma_decB<64,128,4,0>), dim3(512,1),  dim3(256), 0, stream, qb,  wd1, db1, d1o);
    hipLaunchKernelGGL((mfma_decB<128,64,4,1>), dim3(512,4),  dim3(256), 0, stream, d1o, wd2, db2, d2o);
    hipLaunchKernelGGL((mfma_decB<64,32,5,1>),  dim3(2048,4), dim3(256), 0, stream, d2o, wd3, db3, d3o);
    hipLaunchKernelGGL(dec4_mfma, dim3(2048), dim3(256), 0, stream, d3o, wb4, db4, outy);
}

// Round 10
// 526.859 us; speedup vs baseline: 1.8124x; 1.0011x over previous
//
#include <hip/hip_runtime.h>
#include <hip/hip_bf16.h>

typedef __bf16 bf16x8_t __attribute__((ext_vector_type(8)));
typedef float  f32x4_t  __attribute__((ext_vector_type(4)));

__device__ inline bf16x8_t ld_bf16x8(const __hip_bfloat16* p) {
    return *reinterpret_cast<const bf16x8_t*>(p);
}
__device__ inline bf16x8_t zero_bf16x8() {
    bf16x8_t z;
#pragma unroll
    for (int i = 0; i < 8; ++i) z[i] = (__bf16)0.0f;
    return z;
}

// Exact 3-way bf16 split: v == h + m + l exactly (truncation-based).
__device__ inline void split3f(float v, __bf16& h, __bf16& m, __bf16& l) {
    unsigned u;  __builtin_memcpy(&u, &v, 4);
    unsigned uh = u & 0xffff0000u;
    float fh;    __builtin_memcpy(&fh, &uh, 4);
    float r = v - fh;
    unsigned ur; __builtin_memcpy(&ur, &r, 4);
    unsigned um = ur & 0xffff0000u;
    float fm;    __builtin_memcpy(&fm, &um, 4);
    float r2 = r - fm;
    unsigned ul; __builtin_memcpy(&ul, &r2, 4);
    unsigned short hs = (unsigned short)(uh >> 16);
    unsigned short ms = (unsigned short)(um >> 16);
    unsigned short ls = (unsigned short)(ul >> 16);
    __builtin_memcpy(&h, &hs, 2);
    __builtin_memcpy(&m, &ms, 2);
    __builtin_memcpy(&l, &ls, 2);
}

// ---------------------------------------------------------------------------
// enc1: conv 4x4 s2 pad1, CIN=3, COUT=32, exact fp32 (validated).
// ---------------------------------------------------------------------------
__global__ __launch_bounds__(256) void enc1_kernel(
    const float* __restrict__ x, const float* __restrict__ w,
    const float* __restrict__ bias, float* __restrict__ y)
{
    __shared__ float xs[34*66*3];
    __shared__ float wsm[1536];

    const int n  = blockIdx.x >> 3;
    const int th = (blockIdx.x >> 1) & 3;
    const int tw = blockIdx.x & 1;
    const int HO0 = th*16, WO0 = tw*32;
    const int HI0 = 2*HO0 - 1, WI0 = 2*WO0 - 1;
    const int t = threadIdx.x;

    for (int i = t; i < 1536; i += 256) wsm[i] = w[i];
    for (int i = t; i < 34*66*3; i += 256) {
        int row = i / 198; int j = i - row*198;
        int wi_l = j / 3;  int c = j - wi_l*3;
        int hi = HI0 + row, wi = WI0 + wi_l;
        float v = 0.0f;
        if (hi >= 0 && hi < 128 && wi >= 0 && wi < 128)
            v = x[((n*128 + hi)*128 + wi)*3 + c];
        xs[i] = v;
    }
    __syncthreads();

    const int wl = t & 15, hl = t >> 4;
    float acc0[32], acc1[32];
#pragma unroll
    for (int f4 = 0; f4 < 8; ++f4) {
        float4 bv = *(const float4*)(bias + 4*f4);
        acc0[4*f4+0]=bv.x; acc0[4*f4+1]=bv.y; acc0[4*f4+2]=bv.z; acc0[4*f4+3]=bv.w;
        acc1[4*f4+0]=bv.x; acc1[4*f4+1]=bv.y; acc1[4*f4+2]=bv.z; acc1[4*f4+3]=bv.w;
    }
    for (int r = 0; r < 4; ++r) {
#pragma unroll
        for (int s = 0; s < 4; ++s) {
#pragma unroll
            for (int c = 0; c < 3; ++c) {
                float xv0 = xs[(2*hl + r)*198 + (2*wl + s)*3 + c];
                float xv1 = xs[(2*hl + r)*198 + (2*(wl+16) + s)*3 + c];
                const float* wp = wsm + ((r*4 + s)*3 + c)*32;
#pragma unroll
                for (int f4 = 0; f4 < 8; ++f4) {
                    float4 wv = *(const float4*)(wp + 4*f4);
                    acc0[4*f4+0] = fmaf(xv0, wv.x, acc0[4*f4+0]);
                    acc0[4*f4+1] = fmaf(xv0, wv.y, acc0[4*f4+1]);
                    acc0[4*f4+2] = fmaf(xv0, wv.z, acc0[4*f4+2]);
                    acc0[4*f4+3] = fmaf(xv0, wv.w, acc0[4*f4+3]);
                    acc1[4*f4+0] = fmaf(xv1, wv.x, acc1[4*f4+0]);
                    acc1[4*f4+1] = fmaf(xv1, wv.y, acc1[4*f4+1]);
                    acc1[4*f4+2] = fmaf(xv1, wv.z, acc1[4*f4+2]);
                    acc1[4*f4+3] = fmaf(xv1, wv.w, acc1[4*f4+3]);
                }
            }
        }
    }
    float* y0 = y + ((size_t)((n*64 + HO0 + hl)*64) + WO0 + wl)*32;
#pragma unroll
    for (int f4 = 0; f4 < 8; ++f4) {
        float4 o0 = make_float4(fmaxf(acc0[4*f4+0],0.f), fmaxf(acc0[4*f4+1],0.f),
                                fmaxf(acc0[4*f4+2],0.f), fmaxf(acc0[4*f4+3],0.f));
        *(float4*)(y0 + 4*f4) = o0;
    }
    float* y1 = y0 + 16*32;
#pragma unroll
    for (int f4 = 0; f4 < 8; ++f4) {
        float4 o1 = make_float4(fmaxf(acc1[4*f4+0],0.f), fmaxf(acc1[4*f4+1],0.f),
                                fmaxf(acc1[4*f4+2],0.f), fmaxf(acc1[4*f4+3],0.f));
        *(float4*)(y1 + 4*f4) = o1;
    }
}

// ---------------------------------------------------------------------------
// Weight prep (validated layouts).
// ---------------------------------------------------------------------------
__global__ void prep_wpk(const float* __restrict__ w, __hip_bfloat16* __restrict__ out,
                         int TAPS, int CIN, int COUT)
{
    const int NF = COUT >> 4, KC = CIN >> 5;
    int total = TAPS*3*NF*KC*512;
    int i = blockIdx.x*256 + threadIdx.x;
    if (i >= total) return;
    int tmp = i;
    int j = tmp & 7;      tmp >>= 3;
    int lane = tmp & 63;  tmp >>= 6;
    int kc = tmp % KC;    tmp /= KC;
    int nf = tmp % NF;    tmp /= NF;
    int plane = tmp % 3;  int tap = tmp / 3;
    int l15 = lane & 15, quad = lane >> 4;
    int f = nf*16 + l15;
    int c = kc*32 + quad*8 + j;
    float v = w[(tap*CIN + c)*COUT + f];
    __bf16 h, m, l;
    split3f(v, h, m, l);
    ((__bf16*)out)[i] = (plane == 0) ? h : (plane == 1) ? m : l;
}

__global__ void prep_wdk(const float* __restrict__ w, __hip_bfloat16* __restrict__ out,
                         int TAPS, int CIN, int COUT)
{
    const int NF = COUT >> 4, KC = CIN >> 5;
    int total = TAPS*NF*KC*512;
    int i = blockIdx.x*256 + threadIdx.x;
    if (i >= total) return;
    int tmp = i;
    int j = tmp & 7;      tmp >>= 3;
    int lane = tmp & 63;  tmp >>= 6;
    int kc = tmp % KC;    tmp /= KC;
    int nf = tmp % NF;    tmp /= NF;
    int tap = tmp;
    int l15 = lane & 15, quad = lane >> 4;
    int f = nf*16 + l15;
    int c = kc*32 + quad*8 + j;
    out[i] = __float2bfloat16(w[(tap*CIN + c)*COUT + f]);
}

__global__ void prep_wb4(const float* __restrict__ w, __hip_bfloat16* __restrict__ out)
{
    int i = blockIdx.x*256 + threadIdx.x;
    if (i >= 16*64*8) return;
    int j = i & 7;
    int lane = (i >> 3) & 63;
    int g = i >> 9;
    int f = lane & 15;
    int c = (lane >> 4)*8 + j;
    float v = (f < 3) ? w[g*96 + c*3 + f] : 0.0f;
    out[i] = __float2bfloat16(v);
}

// ---------------------------------------------------------------------------
// bf16x3 MFMA encoder conv, B staged per-tap in LDS. NSPLIT divides the
// COUT tiles across blockIdx.y (halves LDS chunk, doubles grid) — total
// staging traffic & MFMA count unchanged, occupancy up. Bit-identical math.
// ---------------------------------------------------------------------------
template<int R,int S,int CIN,int COUT,int IWL,int OWL,int STR,int PAD,int ACT,int INF32,int OUTF32,int NSPLIT>
__global__ __launch_bounds__(256) void mfma_encB(
    const void* __restrict__ xin,
    const __hip_bfloat16* __restrict__ wpk,
    const float* __restrict__ bias,
    __hip_bfloat16* __restrict__ yout,
    float* __restrict__ yf)
{
    constexpr int IW = 1 << IWL, OW = 1 << OWL;
    constexpr int NF = COUT / 16, KC = CIN / 32, TAPS = R*S;
    constexpr int NFB = NF / NSPLIT;
    constexpr int PIECE = NFB*KC*64;           // bf16x8 units per plane piece
    constexpr int CHUNK8 = 3*PIECE;
    __shared__ bf16x8_t ldsB[CHUNK8];

    const int nf0 = (int)blockIdx.y * NFB;
    const int t = threadIdx.x;
    const int wave = t >> 6, lane = t & 63;
    const int l15 = lane & 15, quad = lane >> 4;

    const int m  = blockIdx.x*64 + wave*16 + l15;
    const int wp_ = m & (OW-1);
    const int hp_ = (m >> OWL) & (OW-1);
    const int np_ = m >> (2*OWL);

    f32x4_t acc[NFB];
#pragma unroll
    for (int nf = 0; nf < NFB; ++nf) {
        float bv = bias[(nf0 + nf)*16 + l15];
        acc[nf][0] = bv; acc[nf][1] = bv; acc[nf][2] = bv; acc[nf][3] = bv;
    }
    const bf16x8_t zv = zero_bf16x8();

    for (int tap = 0; tap < TAPS; ++tap) {
        __syncthreads();
        {
            const bf16x8_t* base = (const bf16x8_t*)wpk + (size_t)tap*(3*NF*KC*64);
            for (int i8 = t; i8 < CHUNK8; i8 += 256) {
                int plane = i8 / PIECE;
                int rem = i8 - plane*PIECE;
                ldsB[i8] = base[(size_t)(plane*NF + nf0)*KC*64 + rem];
            }
        }
        __syncthreads();

        const int r = tap / S, s = tap % S;
        const int hi = hp_*STR - PAD + r;
        const int wi = wp_*STR - PAD + s;
        const bool v = (hi >= 0) && (hi < IW) && (wi >= 0) && (wi < IW);
        const int hic = v ? hi : 0, wic = v ? wi : 0;
        const size_t pix = (size_t)(np_*IW + hic)*IW + wic;

#pragma unroll
        for (int kc = 0; kc < KC; ++kc) {
            bf16x8_t ah, am_, al_;
            if (INF32) {
                const float* af = (const float*)xin + pix*CIN + kc*32 + quad*8;
                float xv[8];
                if (v) {
                    *(float4*)(xv+0) = *(const float4*)(af);
                    *(float4*)(xv+4) = *(const float4*)(af + 4);
                } else {
#pragma unroll
                    for (int jj = 0; jj < 8; ++jj) xv[jj] = 0.0f;
                }
#pragma unroll
                for (int jj = 0; jj < 8; ++jj) {
                    __bf16 th, tm, tl;
                    split3f(xv[jj], th, tm, tl);
                    ah[jj] = th; am_[jj] = tm; al_[jj] = tl;
                }
            } else {
                const __hip_bfloat16* ap = (const __hip_bfloat16*)xin
                    + pix*(3*CIN) + kc*32 + quad*8;
                ah  = v ? ld_bf16x8(ap)           : zv;
                am_ = v ? ld_bf16x8(ap + CIN)     : zv;
                al_ = v ? ld_bf16x8(ap + 2*CIN)   : zv;
            }
#pragma unroll
            for (int nf = 0; nf < NFB; ++nf) {
                bf16x8_t bh = ldsB[(0*NFB + nf)*KC*64 + kc*64 + lane];
                bf16x8_t bm = ldsB[(1*NFB + nf)*KC*64 + kc*64 + lane];
                bf16x8_t bl = ldsB[(2*NFB + nf)*KC*64 + kc*64 + lane];
                acc[nf] = __builtin_amdgcn_mfma_f32_16x16x32_bf16(al_, bh, acc[nf], 0, 0, 0);
                acc[nf] = __builtin_amdgcn_mfma_f32_16x16x32_bf16(ah,  bl, acc[nf], 0, 0, 0);
                acc[nf] = __builtin_amdgcn_mfma_f32_16x16x32_bf16(am_, bm, acc[nf], 0, 0, 0);
                acc[nf] = __builtin_amdgcn_mfma_f32_16x16x32_bf16(am_, bh, acc[nf], 0, 0, 0);
                acc[nf] = __builtin_amdgcn_mfma_f32_16x16x32_bf16(ah,  bm, acc[nf], 0, 0, 0);
                acc[nf] = __builtin_amdgcn_mfma_f32_16x16x32_bf16(ah,  bh, acc[nf], 0, 0, 0);
            }
        }
    }

#pragma unroll
    for (int nf = 0; nf < NFB; ++nf) {
#pragma unroll
        for (int i = 0; i < 4; ++i) {
            int mo = blockIdx.x*64 + wave*16 + quad*4 + i;
            int wo = mo & (OW-1), ho = (mo >> OWL) & (OW-1), no = mo >> (2*OWL);
            size_t opix = (size_t)(no*OW + ho)*OW + wo;
            float vv = acc[nf][i];
            if (ACT) vv = fmaxf(vv, 0.0f);
            if (OUTF32) {
                yf[opix*COUT + (nf0 + nf)*16 + l15] = vv;
            } else {
                __bf16 h, mm2, l;
                split3f(vv, h, mm2, l);
                __bf16* yb = (__bf16*)yout + opix*(3*COUT) + (nf0 + nf)*16 + l15;
                yb[0]        = h;
                yb[COUT]     = mm2;
                yb[2*COUT]   = l;
            }
        }
    }
}

// ---------------------------------------------------------------------------
// MFMA decoder layer, B staged per-tap in LDS; NSPLIT over blockIdx.z
// (CONVT) / blockIdx.y (plain conv).
// ---------------------------------------------------------------------------
template<int CIN,int COUT,int SWL,int CONVT,int NSPLIT>
__global__ __launch_bounds__(256) void mfma_decB(
    const __hip_bfloat16* __restrict__ xin,
    const __hip_bfloat16* __restrict__ wdk,
    const float* __restrict__ bias,
    __hip_bfloat16* __restrict__ yout)
{
    constexpr int SW = 1 << SWL;
    constexpr int NF = COUT / 16, KC = CIN / 32;
    constexpr int NFB = NF / NSPLIT;
    constexpr int CHUNK8 = NFB*KC*64;
    __shared__ bf16x8_t ldsB[CHUNK8];

    const int ph = CONVT ? (int)(blockIdx.y >> 1) : 0;
    const int pw = CONVT ? (int)(blockIdx.y & 1) : 0;
    const int nf0 = (CONVT ? (int)blockIdx.z : (int)blockIdx.y) * NFB;
    const int t = threadIdx.x;
    const int wave = t >> 6, lane = t & 63;
    const int l15 = lane & 15, quad = lane >> 4;

    const int m  = blockIdx.x*64 + wave*16 + l15;
    const int wp_ = m & (SW-1);
    const int hp_ = (m >> SWL) & (SW-1);
    const int np_ = m >> (2*SWL);

    f32x4_t acc[NFB];
#pragma unroll
    for (int nf = 0; nf < NFB; ++nf) {
        float bv = bias[(nf0 + nf)*16 + l15];
        acc[nf][0] = bv; acc[nf][1] = bv; acc[nf][2] = bv; acc[nf][3] = bv;
    }
    const bf16x8_t zv = zero_bf16x8();

    for (int tap = 0; tap < 4; ++tap) {
        const int rr = tap >> 1, ss = tap & 1;
        const int widx = CONVT ? ((ph + 2*rr)*4 + (pw + 2*ss)) : tap;
        __syncthreads();
        {
            const bf16x8_t* base = (const bf16x8_t*)wdk
                + (size_t)widx*(NF*KC*64) + (size_t)nf0*KC*64;
            for (int i8 = t; i8 < CHUNK8; i8 += 256) ldsB[i8] = base[i8];
        }
        __syncthreads();

        const int hi = hp_ + ph - 1 + rr;
        const int wi = wp_ + pw - 1 + ss;
        const bool v = (hi >= 0) && (hi < SW) && (wi >= 0) && (wi < SW);
        const int hic = v ? hi : 0, wic = v ? wi : 0;
        const __hip_bfloat16* ap = xin + (size_t)((np_*SW + hic)*SW + wic)*CIN + quad*8;
#pragma unroll
        for (int kc = 0; kc < KC; ++kc) {
            bf16x8_t a = v ? ld_bf16x8(ap + kc*32) : zv;
#pragma unroll
            for (int nf = 0; nf < NFB; ++nf) {
                bf16x8_t b = ldsB[(nf*KC + kc)*64 + lane];
                acc[nf] = __builtin_amdgcn_mfma_f32_16x16x32_bf16(a, b, acc[nf], 0, 0, 0);
            }
        }
    }

    constexpr int HOUT = CONVT ? 2*SW : SW;
#pragma unroll
    for (int nf = 0; nf < NFB; ++nf) {
#pragma unroll
        for (int i = 0; i < 4; ++i) {
            int mo = blockIdx.x*64 + wave*16 + quad*4 + i;
            int wo = mo & (SW-1), ho = (mo >> SWL) & (SW-1), no = mo >> (2*SWL);
            int hoo = CONVT ? 2*ho + ph : ho;
            int woo = CONVT ? 2*wo + pw : wo;
            float vv = fmaxf(acc[nf][i], 0.0f);
            yout[((size_t)(no*HOUT + hoo)*HOUT + woo)*COUT + (nf0 + nf)*16 + l15] = __float2bfloat16(vv);
        }
    }
}

// ---------------------------------------------------------------------------
// dec4 via MFMA (validated r9).
// ---------------------------------------------------------------------------
__global__ __launch_bounds__(256) void dec4_mfma(
    const __hip_bfloat16* __restrict__ x, const __hip_bfloat16* __restrict__ wb,
    const float* __restrict__ bias, float* __restrict__ y)
{
    __shared__ __hip_bfloat16 xs[6*66*40];

    const int n  = blockIdx.x >> 4;
    const int R0 = (blockIdx.x & 15) * 4;
    const int t  = threadIdx.x;
    const int wave = t >> 6, lane = t & 63;
    const int l15 = lane & 15, quad = lane >> 4;

    bf16x8_t wreg[16];
#pragma unroll
    for (int g = 0; g < 16; ++g)
        wreg[g] = ld_bf16x8(wb + (size_t)(g*64 + lane)*8);

    const float bv = (l15 < 3) ? bias[l15] : 0.0f;

    for (int slot = t; slot < 6*66*4; slot += 256) {
        int row = slot / 264;
        int rem = slot - row*264;
        int col = rem >> 2, c8 = rem & 3;
        int xi = R0 - 1 + row, xc = col - 1;
        uint4 val = make_uint4(0u,0u,0u,0u);
        if (xi >= 0 && xi < 64 && xc >= 0 && xc < 64)
            val = *(const uint4*)(x + ((size_t)((n*64 + xi)*64) + xc)*32 + c8*8);
        *(uint4*)(xs + (row*66 + col)*40 + c8*8) = val;
    }
    __syncthreads();

    for (int r4 = 0; r4 < 4; ++r4) {
        bf16x8_t af[3][3];
#pragma unroll
        for (int dr = 0; dr < 3; ++dr)
#pragma unroll
            for (int dc = 0; dc < 3; ++dc)
                af[dr][dc] = *(const bf16x8_t*)(xs
                    + ((r4 + dr)*66 + (wave*16 + l15 + dc))*40 + quad*8);

#pragma unroll
        for (int ph = 0; ph < 2; ++ph)
#pragma unroll
        for (int pw = 0; pw < 2; ++pw) {
            f32x4_t acc;
            acc[0] = bv; acc[1] = bv; acc[2] = bv; acc[3] = bv;
#pragma unroll
            for (int rr = 0; rr < 2; ++rr)
#pragma unroll
            for (int ss = 0; ss < 2; ++ss) {
                const int g = (ph + 2*rr)*4 + (pw + 2*ss);
                acc = __builtin_amdgcn_mfma_f32_16x16x32_bf16(
                          af[ph+rr][pw+ss], wreg[g], acc, 0, 0, 0);
            }
            if (l15 < 3) {
#pragma unroll
                for (int i = 0; i < 4; ++i) {
                    int pc = wave*16 + quad*4 + i;
                    int ho = 2*(R0 + r4) + ph, wo = 2*pc + pw;
                    float vv = 1.0f / (1.0f + __expf(-acc[i]));
                    y[((size_t)(n*128 + ho)*128 + wo)*3 + l15] = vv;
                }
            }
        }
    }
}

__global__ void zero_loss(float* p) {
    if (threadIdx.x == 0 && blockIdx.x == 0) *p = 0.0f;
}

// ---- VQ (exact fp32 distances; q emitted as bf16) ----
__global__ __launch_bounds__(256) void vq_kernel(
    const float* __restrict__ z, const float* __restrict__ emb,
    __hip_bfloat16* __restrict__ qb, float* __restrict__ idx_out,
    float* __restrict__ loss_out, float loss_scale)
{
    __shared__ float zs[64*65];
    __shared__ float es[64*64];
    __shared__ float gd[4*64];
    __shared__ int   gi[4*64];
    __shared__ float md[64];
    __shared__ int   mi[64];

    const int t = threadIdx.x;
    const int pos0 = blockIdx.x * 64;

    for (int j = t; j < 64*64; j += 256)
        zs[(j >> 6)*65 + (j & 63)] = z[pos0*64 + j];
    __syncthreads();

    const int pos = t & 63;
    const int grp = t >> 6;
    float zr[64];
#pragma unroll
    for (int d = 0; d < 64; ++d) zr[d] = zs[pos*65 + d];

    float bestd = 3.4e38f;
    int   besti = 0;

    for (int ck = 0; ck < 8; ++ck) {
        __syncthreads();
        for (int j = t; j < 4096; j += 256) es[j] = emb[ck*4096 + j];
        __syncthreads();
#pragma unroll
        for (int k = 0; k < 16; ++k) {
            const int cc = grp + 4*k;
            const float4* ep = (const float4*)(es + cc*64);
            float acc = 0.0f;
#pragma unroll
            for (int u = 0; u < 16; ++u) {
                float4 e = ep[u];
                float d0 = zr[4*u+0] - e.x;
                float d1 = zr[4*u+1] - e.y;
                float d2 = zr[4*u+2] - e.z;
                float d3 = zr[4*u+3] - e.w;
                acc = fmaf(d0,d0,acc); acc = fmaf(d1,d1,acc);
                acc = fmaf(d2,d2,acc); acc = fmaf(d3,d3,acc);
            }
            const int code = ck*64 + cc;
            if (acc < bestd) { bestd = acc; besti = code; }
        }
    }
    gd[grp*64 + pos] = bestd;
    gi[grp*64 + pos] = besti;
    __syncthreads();
    if (grp == 0) {
        float bd = gd[pos]; int bi = gi[pos];
#pragma unroll
        for (int g2 = 1; g2 < 4; ++g2) {
            float dv = gd[g2*64 + pos]; int iv = gi[g2*64 + pos];
            if (dv < bd || (dv == bd && iv < bi)) { bd = dv; bi = iv; }
        }
        md[pos] = bd; mi[pos] = bi;
        idx_out[pos0 + pos] = (float)bi;
    }
    __syncthreads();
    for (int j = t; j < 4096; j += 256) {
        int p = j >> 6, d = j & 63;
        qb[pos0*64 + j] = __float2bfloat16(emb[mi[p]*64 + d]);
    }
    if (t == 0) {
        float s = 0.0f;
        for (int p = 0; p < 64; ++p) s += md[p];
        atomicAdd(loss_out, s * loss_scale);
    }
}

extern "C" void kernel_launch(void* const* d_in, const int* in_sizes, int n_in,
                              void* d_out, int out_size, void* d_ws, size_t ws_size,
                              hipStream_t stream)
{
    const float* x   = (const float*)d_in[0];
    const float* ew1 = (const float*)d_in[1];  const float* eb1 = (const float*)d_in[2];
    const float* ew2 = (const float*)d_in[3];  const float* eb2 = (const float*)d_in[4];
    const float* ew3 = (const float*)d_in[5];  const float* eb3 = (const float*)d_in[6];
    const float* ew4 = (const float*)d_in[7];  const float* eb4 = (const float*)d_in[8];
    const float* emb = (const float*)d_in[9];
    const float* dw1 = (const float*)d_in[10]; const float* db1 = (const float*)d_in[11];
    const float* dw2 = (const float*)d_in[12]; const float* db2 = (const float*)d_in[13];
    const float* dw3 = (const float*)d_in[14]; const float* db3 = (const float*)d_in[15];
    const float* dw4 = (const float*)d_in[16]; const float* db4 = (const float*)d_in[17];

    float* outy = (float*)d_out;          // y: 6291456
    float* outl = outy + 6291456;         // loss: 1
    float* outi = outl + 1;               // idx: 32768

    // Workspace layout (time-multiplexed; peak < 134,217,728 B):
    char* W = (char*)d_ws;
    float*          e1  = (float*)         (W + 0);          // 64 MB [0,67108864)
    __hip_bfloat16* e2p = (__hip_bfloat16*)(W + 67108864);   // 50.3 MB
    __hip_bfloat16* e3p = (__hip_bfloat16*)(W + 0);          // 25.2 MB (over dead e1)
    float*          z   = (float*)         (W + 25165824);   // 8 MB
    __hip_bfloat16* qb  = (__hip_bfloat16*)(W + 33554432);   // 4 MB
    __hip_bfloat16* d1o = (__hip_bfloat16*)(W + 37748736);   // 8.4 MB
    __hip_bfloat16* d2o = (__hip_bfloat16*)(W + 46137344);   // 16.8 MB
    __hip_bfloat16* d3o = (__hip_bfloat16*)(W + 67108864);   // 33.6 MB (over dead e2p)
    // persistent weights:
    __hip_bfloat16* wp2 = (__hip_bfloat16*)(W + 117440512);  //  98304 el
    __hip_bfloat16* wp3 = wp2 + 98304;                       // 393216 el
    __hip_bfloat16* wp4 = wp3 + 393216;                      //  98304 el
    __hip_bfloat16* wd1 = wp4 + 98304;                       //  32768 el
    __hip_bfloat16* wd2 = wd1 + 32768;                       // 131072 el
    __hip_bfloat16* wd3 = wd2 + 131072;                      //  32768 el
    __hip_bfloat16* wb4 = wd3 + 32768;                       //   8192 el

    // ---- weight prep ----
    hipLaunchKernelGGL(prep_wpk, dim3(384),  dim3(256), 0, stream, ew2, wp2, 16, 32, 64);
    hipLaunchKernelGGL(prep_wpk, dim3(1536), dim3(256), 0, stream, ew3, wp3, 16, 64, 128);
    hipLaunchKernelGGL(prep_wpk, dim3(384),  dim3(256), 0, stream, ew4, wp4, 4, 128, 64);
    hipLaunchKernelGGL(prep_wdk, dim3(128),  dim3(256), 0, stream, dw1, wd1, 4, 64, 128);
    hipLaunchKernelGGL(prep_wdk, dim3(512),  dim3(256), 0, stream, dw2, wd2, 16, 128, 64);
    hipLaunchKernelGGL(prep_wdk, dim3(128),  dim3(256), 0, stream, dw3, wd3, 16, 64, 32);
    hipLaunchKernelGGL(prep_wb4, dim3(32),   dim3(256), 0, stream, dw4, wb4);

    // ---- encoder (fp32-accurate bf16x3 MFMA, B in LDS) ----
    hipLaunchKernelGGL(enc1_kernel, dim3(1024), dim3(256), 0, stream, x, ew1, eb1, e1);
    hipLaunchKernelGGL((mfma_encB<4,4,32,64,6,5,2,1,1,1,0,1>), dim3(2048), dim3(256), 0, stream,
                       (const void*)e1, wp2, eb2, e2p, (float*)nullptr);
    hipLaunchKernelGGL((mfma_encB<4,4,64,128,5,4,2,1,1,0,0,2>), dim3(512,2), dim3(256), 0, stream,
                       (const void*)e2p, wp3, eb3, e3p, (float*)nullptr);
    hipLaunchKernelGGL((mfma_encB<2,2,128,64,4,4,1,0,0,0,1,2>), dim3(512,2), dim3(256), 0, stream,
                       (const void*)e3p, wp4, eb4, (__hip_bfloat16*)nullptr, z);

    // ---- vector quantizer ----
    hipLaunchKernelGGL(zero_loss, dim3(1), dim3(64), 0, stream, outl);
    hipLaunchKernelGGL(vq_kernel, dim3(512), dim3(256), 0, stream,
                       z, emb, qb, outi, outl, 0.25f / 2097152.0f);

    // ---- decoder (bf16 MFMA, B in LDS) ----
    hipLaunchKernelGGL((mfma_decB<64,128,4,0,2>), dim3(512,2),  dim3(256), 0, stream, qb,  wd1, db1, d1o);
    hipLaunchKernelGGL((mfma_decB<128,64,4,1,1>), dim3(512,4),  dim3(256), 0, stream, d1o, wd2, db2, d2o);
    hipLaunchKernelGGL((mfma_decB<64,32,5,1,1>),  dim3(2048,4), dim3(256), 0, stream, d2o, wd3, db3, d3o);
    hipLaunchKernelGGL(dec4_mfma, dim3(2048), dim3(256), 0, stream, d3o, wb4, db4, outy);
}